// Round 2
// baseline (14454.468 us; speedup 1.0000x reference)
//
#include <hip/hip_runtime.h>
#include <hip/hip_bf16.h>
#include <hip/hip_cooperative_groups.h>

namespace cg = cooperative_groups;

#define N2   2048
#define CH   256
#define FFNC 1024

// ---------------- workspace layout (float offsets) ----------------
#define OFF_Q      0u                        // [2][2048][2048]
#define OFF_Y      0u                        // [2][2048][256]  (reuses Q; Q dead after att_gemm)
#define OFF_IMFT   8388608u                  // [2][2048][256]  img feat transposed
#define OFF_XCAT   (OFF_IMFT + 1048576u)     // [2][2048][512]  concat(pf, att)
#define OFF_PCLS   (OFF_XCAT + 2097152u)     // [2][2048]
#define OFF_ICLS   (OFF_PCLS + 4096u)
#define OFF_AVEC   (OFF_ICLS + 4096u)
#define OFF_CPART  (OFF_AVEC + 4096u)        // [2][8][2048] column-sum partials
#define OFF_WOUTT  (OFF_CPART + 32768u)      // [512][256]
#define OFF_WF1T   (OFF_WOUTT + 131072u)     // [256][1024]
#define OFF_WF2T   (OFF_WF1T + 262144u)      // [1024][256]
#define OFF_WPT    (OFF_WF2T + 262144u)      // [256][256]
#define OFF_WIT    (OFF_WPT + 65536u)        // [256][256]
#define OFF_Y2     OFF_XCAT                  // reuse (xcat dead after outproj)

// ---------------- helpers ----------------
__device__ __forceinline__ void blockReduce2(float& x, float& y, float* sred) {
    #pragma unroll
    for (int off = 32; off; off >>= 1) {
        x += __shfl_xor(x, off);
        y += __shfl_xor(y, off);
    }
    const int wave = threadIdx.x >> 6, lane = threadIdx.x & 63;
    if (lane == 0) { sred[wave] = x; sred[4 + wave] = y; }
    __syncthreads();
    x = sred[0] + sred[1] + sred[2] + sred[3];
    y = sred[4] + sred[5] + sred[6] + sred[7];
    __syncthreads();
}

// ---------------- tiny prep kernels ----------------
__global__ void __launch_bounds__(256) cls_max_k(
    const float* __restrict__ pc, const float* __restrict__ ic,
    float* __restrict__ pcls, float* __restrict__ icls) {
    const int g = blockIdx.x * 256 + threadIdx.x;  // 4096
    const int b = g >> 11, n = g & 2047;
    float m1 = -1e30f, m2 = -1e30f;
    #pragma unroll
    for (int k = 0; k < 10; ++k) {
        const float v1 = pc[((size_t)b * 10 + k) * N2 + n];
        const float v2 = ic[((size_t)b * 10 + k) * N2 + n];
        m1 = fmaxf(m1, 1.f / (1.f + __expf(-v1)));
        m2 = fmaxf(m2, 1.f / (1.f + __expf(-v2)));
    }
    pcls[g] = m1; icls[g] = m2;
}

__global__ void __launch_bounds__(256) transpose_k(
    const float* __restrict__ in, float* __restrict__ out, int R, int C) {
    __shared__ float t[32][33];
    const int nct = C >> 5;
    const int bx = blockIdx.x % nct, by = blockIdx.x / nct;
    const int c0 = bx * 32, r0 = by * 32;
    const int tx = threadIdx.x & 31, ty = threadIdx.x >> 5;
    #pragma unroll
    for (int i = 0; i < 4; ++i) {
        const int r = ty + i * 8;
        t[r][tx] = in[(size_t)(r0 + r) * C + c0 + tx];
    }
    __syncthreads();
    #pragma unroll
    for (int i = 0; i < 4; ++i) {
        const int r = ty + i * 8;
        out[(size_t)(c0 + r) * R + r0 + tx] = t[tx][r];
    }
}

// proj + pos-embed: out[b][n][o] = sum_c WT[c][o]*F[b][c][n] + bias[o]+bpos[o]+Wpos[o]·pos[b][n]
__global__ void __launch_bounds__(256) proj_rows(
    const float* __restrict__ F, const float* __restrict__ WT,
    const float* __restrict__ bias, const float* __restrict__ Wpos,
    const float* __restrict__ bpos, const float* __restrict__ pos,
    float* __restrict__ outb, int ostride) {
    const int b = blockIdx.x >> 8;
    const int n0 = (blockIdx.x & 255) * 8;
    const int tid = threadIdx.x;
    __shared__ float s_x[8][256];
    for (int idx = tid; idx < 2048; idx += 256) {
        const int r = idx & 7, c = idx >> 3;
        s_x[r][c] = F[((size_t)b * CH + c) * N2 + n0 + r];
    }
    __syncthreads();
    float acc[8] = {0, 0, 0, 0, 0, 0, 0, 0};
    for (int c = 0; c < 256; ++c) {
        const float w = WT[(size_t)c * CH + tid];
        #pragma unroll
        for (int r = 0; r < 8; ++r) acc[r] += s_x[r][c] * w;
    }
    const float badd = bias[tid] + bpos[tid];
    const float w0 = Wpos[tid * 2 + 0], w1 = Wpos[tid * 2 + 1];
    #pragma unroll
    for (int r = 0; r < 8; ++r) {
        const int n = n0 + r;
        const float p0 = pos[((size_t)b * N2 + n) * 2 + 0];
        const float p1 = pos[((size_t)b * N2 + n) * 2 + 1];
        outb[((size_t)b * N2 + n) * ostride + tid] = acc[r] + badd + w0 * p0 + w1 * p1;
    }
}

// ---------------- the cooperative IPOT kernel ----------------
// grid 512 (256 blocks/batch), block 256.  Iterates on Q:
//   Q_{t+1} = max(G * a_t*Q_t*b_t, 1e-6), fused with rowdot_{t+1} = Q_{t+1}·b_t.
__global__ void __launch_bounds__(256, 2) ipot_coop(
    float* __restrict__ Q, const float* __restrict__ ppos, const float* __restrict__ ipos,
    const float* __restrict__ pcls, const float* __restrict__ icls,
    float* __restrict__ avec, float* __restrict__ cpart) {
    cg::grid_group gridg = cg::this_grid();
    const int blk = blockIdx.x;
    const int b = blk >> 8;
    const int lb = blk & 255;
    const int tid = threadIdx.x;
    const int wave = tid >> 6, lane = tid & 63;

    __shared__ float s_ix[N2], s_iy[N2], s_b[N2];
    __shared__ float s_cred[4][64];

    for (int m = tid; m < N2; m += 256) {
        s_ix[m] = ipos[((size_t)b * N2 + m) * 2 + 0];
        s_iy[m] = ipos[((size_t)b * N2 + m) * 2 + 1];
    }
    __syncthreads();

    float* Qb = Q + (size_t)b * N2 * N2;
    const float* pclsb = pcls + b * N2;
    const float* iclsb = icls + b * N2;
    float* avecb = avec + b * N2;

    // ---- init: Q_1 = max(G,1e-6);  a_1 = pcls/( (sum Q)/N + 1e-6 )
    #pragma unroll
    for (int r = 0; r < 2; ++r) {
        const int row = lb * 8 + wave * 2 + r;
        const float px = ppos[((size_t)b * N2 + row) * 2 + 0];
        const float py = ppos[((size_t)b * N2 + row) * 2 + 1];
        float* qrow = Qb + (size_t)row * N2;
        float racc = 0.f;
        #pragma unroll
        for (int k = 0; k < 8; ++k) {
            const int c0 = (k * 64 + lane) * 4;
            const float4 ix = *(const float4*)&s_ix[c0];
            const float4 iy = *(const float4*)&s_iy[c0];
            float4 qn;
            { float dx = px - ix.x, dy = py - iy.x; qn.x = fmaxf(__expf(-0.1f * sqrtf(dx*dx + dy*dy)), 1e-6f); }
            { float dx = px - ix.y, dy = py - iy.y; qn.y = fmaxf(__expf(-0.1f * sqrtf(dx*dx + dy*dy)), 1e-6f); }
            { float dx = px - ix.z, dy = py - iy.z; qn.z = fmaxf(__expf(-0.1f * sqrtf(dx*dx + dy*dy)), 1e-6f); }
            { float dx = px - ix.w, dy = py - iy.w; qn.w = fmaxf(__expf(-0.1f * sqrtf(dx*dx + dy*dy)), 1e-6f); }
            *(float4*)&qrow[c0] = qn;
            racc += (qn.x + qn.y) + (qn.z + qn.w);
        }
        #pragma unroll
        for (int off = 32; off; off >>= 1) racc += __shfl_xor(racc, off);
        if (lane == 0) {
            const float dot = racc * (1.f / 2048.f);
            avecb[row] = pclsb[row] / (dot + 1e-6f);
        }
    }
    gridg.sync();

    const int cgp = lb & 31;     // column group (64 cols)
    const int chunk = lb >> 5;   // row chunk (256 rows)
    const int colL = tid & 63;
    const int rsub = tid >> 6;
    const int col = cgp * 64 + colL;

    for (int t = 1; t <= 100; ++t) {
        // ---- C pass: coldot partials = Q_t^T a_t over this block's 256-row chunk
        {
            const float* qp = Qb + (size_t)(chunk * 256 + rsub * 64) * N2 + col;
            const float* ap = avecb + chunk * 256 + rsub * 64;
            float a0 = 0, a1 = 0, a2 = 0, a3 = 0;
            for (int r = 0; r < 64; r += 4) {
                a0 += qp[(size_t)(r + 0) * N2] * ap[r + 0];
                a1 += qp[(size_t)(r + 1) * N2] * ap[r + 1];
                a2 += qp[(size_t)(r + 2) * N2] * ap[r + 2];
                a3 += qp[(size_t)(r + 3) * N2] * ap[r + 3];
            }
            s_cred[rsub][colL] = (a0 + a1) + (a2 + a3);
            __syncthreads();
            if (rsub == 0) {
                cpart[((size_t)b * 8 + chunk) * N2 + col] =
                    s_cred[0][colL] + s_cred[1][colL] + s_cred[2][colL] + s_cred[3][colL];
            }
        }
        gridg.sync();

        // ---- b_t from partials (each block builds full s_b for its batch)
        for (int m = tid; m < N2; m += 256) {
            float s = 0.f;
            #pragma unroll
            for (int c = 0; c < 8; ++c) s += cpart[((size_t)b * 8 + c) * N2 + m];
            s_b[m] = iclsb[m] / (s + 1e-6f);
        }
        __syncthreads();

        if (t < 100) {
            // ---- UR pass: Q_{t+1} = max(G*(a*Q*b),1e-6); rowdot = Q_{t+1}·b_t -> a_{t+1}
            #pragma unroll
            for (int r = 0; r < 2; ++r) {
                const int row = lb * 8 + wave * 2 + r;
                const float px = ppos[((size_t)b * N2 + row) * 2 + 0];
                const float py = ppos[((size_t)b * N2 + row) * 2 + 1];
                const float a = avecb[row];
                float* qrow = Qb + (size_t)row * N2;
                float racc = 0.f;
                #pragma unroll
                for (int k = 0; k < 8; ++k) {
                    const int c0 = (k * 64 + lane) * 4;
                    float4 q = *(const float4*)&qrow[c0];
                    const float4 bb = *(const float4*)&s_b[c0];
                    const float4 ix = *(const float4*)&s_ix[c0];
                    const float4 iy = *(const float4*)&s_iy[c0];
                    float4 qn;
                    { float dx = px - ix.x, dy = py - iy.x;
                      const float G = __expf(-0.1f * sqrtf(dx*dx + dy*dy));
                      qn.x = fmaxf(G * ((a * q.x) * bb.x), 1e-6f); racc += qn.x * bb.x; }
                    { float dx = px - ix.y, dy = py - iy.y;
                      const float G = __expf(-0.1f * sqrtf(dx*dx + dy*dy));
                      qn.y = fmaxf(G * ((a * q.y) * bb.y), 1e-6f); racc += qn.y * bb.y; }
                    { float dx = px - ix.z, dy = py - iy.z;
                      const float G = __expf(-0.1f * sqrtf(dx*dx + dy*dy));
                      qn.z = fmaxf(G * ((a * q.z) * bb.z), 1e-6f); racc += qn.z * bb.z; }
                    { float dx = px - ix.w, dy = py - iy.w;
                      const float G = __expf(-0.1f * sqrtf(dx*dx + dy*dy));
                      qn.w = fmaxf(G * ((a * q.w) * bb.w), 1e-6f); racc += qn.w * bb.w; }
                    *(float4*)&qrow[c0] = qn;
                }
                #pragma unroll
                for (int off = 32; off; off >>= 1) racc += __shfl_xor(racc, off);
                if (lane == 0) avecb[row] = pclsb[row] / (racc + 1e-6f);
            }
            gridg.sync();
        } else {
            // ---- F pass: res = a*Q*b, L1-normalize rows, write res~ into Q
            #pragma unroll
            for (int r = 0; r < 2; ++r) {
                const int row = lb * 8 + wave * 2 + r;
                const float a = avecb[row];
                float* qrow = Qb + (size_t)row * N2;
                float4 rv[8];
                float rsum = 0.f;
                #pragma unroll
                for (int k = 0; k < 8; ++k) {
                    const int c0 = (k * 64 + lane) * 4;
                    const float4 q = *(const float4*)&qrow[c0];
                    const float4 bb = *(const float4*)&s_b[c0];
                    rv[k].x = (a * q.x) * bb.x; rv[k].y = (a * q.y) * bb.y;
                    rv[k].z = (a * q.z) * bb.z; rv[k].w = (a * q.w) * bb.w;
                    rsum += (rv[k].x + rv[k].y) + (rv[k].z + rv[k].w);
                }
                #pragma unroll
                for (int off = 32; off; off >>= 1) rsum += __shfl_xor(rsum, off);
                const float sc = 1.f / fmaxf(rsum, 1e-12f);
                #pragma unroll
                for (int k = 0; k < 8; ++k) {
                    const int c0 = (k * 64 + lane) * 4;
                    float4 o;
                    o.x = rv[k].x * sc; o.y = rv[k].y * sc; o.z = rv[k].z * sc; o.w = rv[k].w * sc;
                    *(float4*)&qrow[c0] = o;
                }
            }
        }
    }
}

// ---------------- att GEMM: xcat[b][n][256+c] = sum_m res~[b][n][m] * imfT[b][m][c]
__global__ void __launch_bounds__(256) att_gemm(
    const float* __restrict__ R, const float* __restrict__ V, float* __restrict__ xcat) {
    const int bid = blockIdx.x;               // 2*32*4 = 256
    const int nt = bid & 31, ct = (bid >> 5) & 3, b = bid >> 7;
    const int n0 = nt * 64, c0 = ct * 64;
    __shared__ float sR[64][17];
    __shared__ float sV[16][65];
    const int tid = threadIdx.x;
    const int cx = tid & 15, ny = tid >> 4;
    float acc[4][4] = {};
    const float* Rb = R + (size_t)b * N2 * N2;
    const float* Vb = V + (size_t)b * N2 * CH;
    for (int k0 = 0; k0 < N2; k0 += 16) {
        for (int idx = tid; idx < 1024; idx += 256) {
            const int nl = idx >> 4, kk = idx & 15;
            sR[nl][kk] = Rb[(size_t)(n0 + nl) * N2 + k0 + kk];
        }
        for (int idx = tid; idx < 1024; idx += 256) {
            const int kk = idx >> 6, cl = idx & 63;
            sV[kk][cl] = Vb[(size_t)(k0 + kk) * CH + c0 + cl];
        }
        __syncthreads();
        #pragma unroll
        for (int kk = 0; kk < 16; ++kk) {
            float av[4], bv[4];
            #pragma unroll
            for (int i = 0; i < 4; ++i) av[i] = sR[ny + 16 * i][kk];
            #pragma unroll
            for (int j = 0; j < 4; ++j) bv[j] = sV[kk][cx + 16 * j];
            #pragma unroll
            for (int i = 0; i < 4; ++i)
                #pragma unroll
                for (int j = 0; j < 4; ++j) acc[i][j] += av[i] * bv[j];
        }
        __syncthreads();
    }
    #pragma unroll
    for (int i = 0; i < 4; ++i)
        #pragma unroll
        for (int j = 0; j < 4; ++j)
            xcat[((size_t)b * N2 + n0 + ny + 16 * i) * 512 + 256 + c0 + cx + 16 * j] = acc[i][j];
}

// ---------------- out_projection + LN ----------------
__global__ void __launch_bounds__(256) outproj_k(
    const float* __restrict__ xcat, const float* __restrict__ WoutT,
    const float* __restrict__ bout, const float* __restrict__ g,
    const float* __restrict__ be, float* __restrict__ y) {
    const int b = blockIdx.x >> 8;
    const int n0 = (blockIdx.x & 255) * 8;
    const int tid = threadIdx.x;
    __shared__ float s_x[8][512];
    __shared__ float sred[8];
    for (int idx = tid; idx < 4096; idx += 256) {
        const int k = idx & 511, r = idx >> 9;
        s_x[r][k] = xcat[((size_t)b * N2 + n0 + r) * 512 + k];
    }
    __syncthreads();
    float acc[8] = {0, 0, 0, 0, 0, 0, 0, 0};
    for (int k = 0; k < 512; ++k) {
        const float w = WoutT[(size_t)k * CH + tid];
        #pragma unroll
        for (int r = 0; r < 8; ++r) acc[r] += s_x[r][k] * w;
    }
    const float bo = bout[tid], gg = g[tid], bb = be[tid];
    #pragma unroll
    for (int r = 0; r < 8; ++r) {
        const float v = acc[r] + bo;
        float s1 = v, s2 = v * v;
        blockReduce2(s1, s2, sred);
        const float mu = s1 * (1.f / 256.f);
        const float var = s2 * (1.f / 256.f) - mu * mu;
        y[((size_t)b * N2 + n0 + r) * CH + tid] = (v - mu) * rsqrtf(var + 1e-5f) * gg + bb;
    }
}

// ---------------- fused FFN + residual + LN + pred head ----------------
__global__ void __launch_bounds__(256) ffn_k(
    const float* __restrict__ y, const float* __restrict__ Wf1T,
    const float* __restrict__ bf1, const float* __restrict__ Wf2T,
    const float* __restrict__ bf2, const float* __restrict__ gln,
    const float* __restrict__ bln, const float* __restrict__ Wpred,
    const float* __restrict__ bpred, const float* __restrict__ pos,
    float* __restrict__ y2, float* __restrict__ out1,
    float* __restrict__ out2) {
    const int b = blockIdx.x >> 8;
    const int n0 = (blockIdx.x & 255) * 8;
    const int tid = threadIdx.x;
    __shared__ float s_y[8][256];
    __shared__ float s_h[8][1024];
    __shared__ float sred[8];
    for (int idx = tid; idx < 2048; idx += 256) {
        const int c = idx & 255, r = idx >> 8;
        s_y[r][c] = y[((size_t)b * N2 + n0 + r) * CH + c];
    }
    __syncthreads();
    float acc[4][8] = {};
    for (int c = 0; c < 256; ++c) {
        float yv[8];
        #pragma unroll
        for (int r = 0; r < 8; ++r) yv[r] = s_y[r][c];
        #pragma unroll
        for (int fi = 0; fi < 4; ++fi) {
            const float w = Wf1T[(size_t)c * FFNC + fi * 256 + tid];
            #pragma unroll
            for (int r = 0; r < 8; ++r) acc[fi][r] += yv[r] * w;
        }
    }
    #pragma unroll
    for (int fi = 0; fi < 4; ++fi) {
        const int f = fi * 256 + tid;
        const float bb = bf1[f];
        #pragma unroll
        for (int r = 0; r < 8; ++r) s_h[r][f] = fmaxf(acc[fi][r] + bb, 0.f);
    }
    __syncthreads();
    float a2[8] = {0, 0, 0, 0, 0, 0, 0, 0};
    for (int f = 0; f < 1024; ++f) {
        const float w = Wf2T[(size_t)f * CH + tid];
        #pragma unroll
        for (int r = 0; r < 8; ++r) a2[r] += s_h[r][f] * w;
    }
    const float bfv = bf2[tid], gg = gln[tid], bb2 = bln[tid];
    const float wp0 = Wpred[tid], wp1 = Wpred[CH + tid];
    #pragma unroll
    for (int r = 0; r < 8; ++r) {
        const int n = n0 + r;
        const float v = a2[r] + bfv + s_y[r][tid];
        float s1 = v, s2 = v * v;
        blockReduce2(s1, s2, sred);
        const float mu = s1 * (1.f / 256.f);
        const float var = s2 * (1.f / 256.f) - mu * mu;
        const float xo = (v - mu) * rsqrtf(var + 1e-5f) * gg + bb2;
        y2[((size_t)b * N2 + n) * CH + tid] = xo;
        float d0 = wp0 * xo, d1 = wp1 * xo;
        blockReduce2(d0, d1, sred);
        if (tid == 0) {
            const float c0v = d0 + bpred[0] + pos[((size_t)b * N2 + n) * 2 + 0];
            const float c1v = d1 + bpred[1] + pos[((size_t)b * N2 + n) * 2 + 1];
            out2[((size_t)b * 2 + 0) * N2 + n] = c0v;
            out2[((size_t)b * 2 + 1) * N2 + n] = c1v;
            out1[((size_t)b * N2 + n) * 2 + 0] = c0v;
            out1[((size_t)b * N2 + n) * 2 + 1] = c1v;
        }
    }
}

// ---------------- transpose xo -> out0 [b][c][n] f32 ----------------
__global__ void __launch_bounds__(256) out_x_k(
    const float* __restrict__ y2, float* __restrict__ out0) {
    __shared__ float t[32][33];
    const int bid = blockIdx.x;                      // 2*64*8 = 1024
    const int ct = bid & 7, nt = (bid >> 3) & 63, b = bid >> 9;
    const int tx = threadIdx.x & 31, ty = threadIdx.x >> 5;
    #pragma unroll
    for (int i = 0; i < 4; ++i) {
        const int r = ty + i * 8;
        t[r][tx] = y2[((size_t)b * N2 + nt * 32 + r) * CH + ct * 32 + tx];
    }
    __syncthreads();
    #pragma unroll
    for (int i = 0; i < 4; ++i) {
        const int r = ty + i * 8;
        out0[((size_t)b * CH + ct * 32 + r) * N2 + nt * 32 + tx] = t[tx][r];
    }
}

// ---------------- launcher ----------------
extern "C" void kernel_launch(void* const* d_in, const int* in_sizes, int n_in,
                              void* d_out, int out_size, void* d_ws, size_t ws_size,
                              hipStream_t stream) {
    const float* ptsf  = (const float*)d_in[0];
    const float* ppos  = (const float*)d_in[1];
    const float* imgf  = (const float*)d_in[2];
    const float* ipos  = (const float*)d_in[3];
    const float* pcin  = (const float*)d_in[4];
    const float* icin  = (const float*)d_in[5];
    const float* Wp    = (const float*)d_in[6];
    const float* bp    = (const float*)d_in[7];
    const float* Wi    = (const float*)d_in[8];
    const float* bi    = (const float*)d_in[9];
    const float* Wqp   = (const float*)d_in[10];
    const float* bqp   = (const float*)d_in[11];
    const float* Wkp   = (const float*)d_in[12];
    const float* bkp   = (const float*)d_in[13];
    const float* Wout  = (const float*)d_in[14];
    const float* bout  = (const float*)d_in[15];
    const float* gout  = (const float*)d_in[16];
    const float* beo   = (const float*)d_in[17];
    const float* Wf1   = (const float*)d_in[18];
    const float* bf1   = (const float*)d_in[19];
    const float* Wf2   = (const float*)d_in[20];
    const float* bf2   = (const float*)d_in[21];
    const float* gln   = (const float*)d_in[22];
    const float* bln   = (const float*)d_in[23];
    const float* Wpred = (const float*)d_in[24];
    const float* bpred = (const float*)d_in[25];

    float* ws    = (float*)d_ws;
    float* Q     = ws + OFF_Q;
    float* imfT  = ws + OFF_IMFT;
    float* xcat  = ws + OFF_XCAT;
    float* yb    = ws + OFF_Y;      // overlaps Q (Q dead after att_gemm)
    float* pcls  = ws + OFF_PCLS;
    float* icls  = ws + OFF_ICLS;
    float* avec  = ws + OFF_AVEC;
    float* cpart = ws + OFF_CPART;
    float* WoutT = ws + OFF_WOUTT;
    float* Wf1T  = ws + OFF_WF1T;
    float* Wf2T  = ws + OFF_WF2T;
    float* WpT   = ws + OFF_WPT;
    float* WiT   = ws + OFF_WIT;
    float* y2    = ws + OFF_Y2;

    float* out0 = (float*)d_out;                     // x       [2,256,2048]
    float* out1 = out0 + (size_t)2 * CH * N2;        // new_pos [2,2048,2]
    float* out2 = out1 + (size_t)2 * N2 * 2;         // center  [2,2,2048]

    cls_max_k<<<16, 256, 0, stream>>>(pcin, icin, pcls, icls);
    transpose_k<<<64, 256, 0, stream>>>(Wp, WpT, 256, 256);
    transpose_k<<<64, 256, 0, stream>>>(Wi, WiT, 256, 256);
    transpose_k<<<128, 256, 0, stream>>>(Wout, WoutT, 256, 512);
    transpose_k<<<256, 256, 0, stream>>>(Wf1, Wf1T, 1024, 256);
    transpose_k<<<256, 256, 0, stream>>>(Wf2, Wf2T, 256, 1024);
    proj_rows<<<512, 256, 0, stream>>>(ptsf, WpT, bp, Wqp, bqp, ppos, xcat, 512);
    proj_rows<<<512, 256, 0, stream>>>(imgf, WiT, bi, Wkp, bkp, ipos, imfT, 256);

    {
        void* args[] = {(void*)&Q, (void*)&ppos, (void*)&ipos, (void*)&pcls,
                        (void*)&icls, (void*)&avec, (void*)&cpart};
        hipLaunchCooperativeKernel((void*)ipot_coop, dim3(512), dim3(256),
                                   (void**)args, 0, stream);
    }

    att_gemm<<<256, 256, 0, stream>>>(Q, imfT, xcat);
    outproj_k<<<512, 256, 0, stream>>>(xcat, WoutT, bout, gout, beo, yb);
    ffn_k<<<512, 256, 0, stream>>>(yb, Wf1T, bf1, Wf2T, bf2, gln, bln,
                                   Wpred, bpred, ppos, y2, out1, out2);
    out_x_k<<<1024, 256, 0, stream>>>(y2, out0);
}

// Round 6
// 2644.562 us; speedup vs baseline: 5.4657x; 5.4657x over previous
//
#include <hip/hip_runtime.h>
#include <hip/hip_bf16.h>

#define N2   2048
#define CH   256
#define FFNC 1024

// ---------------- workspace layout (float offsets), total 48.8MB ----------------
#define OFF_Q      0u                        // [2][2048][2048] ; y aliases after att_gemm
#define OFF_IMFT   8388608u                  // [2][2048][256]
#define OFF_PF     9437184u                  // [2][2048][256] ; y2 aliases after outproj
#define OFF_CPART  10485760u                 // [2][256][2048] ; WpT/WiT before ipot, att after
#define OFF_PCLS   11534336u                 // [2][2048]
#define OFF_ICLS   11538432u
#define OFF_BVEC   11542528u
#define OFF_AVEC   11546624u
#define OFF_WOUTT  11550720u                 // [512][256]
#define OFF_WF1T   11681792u                 // [256][1024]
#define OFF_WF2T   11943936u                 // [1024][256]  end = 12206080 floats

// ---------------- helpers ----------------
__device__ __forceinline__ void blockReduce2(float& x, float& y, float* sred) {
    #pragma unroll
    for (int off = 32; off; off >>= 1) {
        x += __shfl_xor(x, off);
        y += __shfl_xor(y, off);
    }
    const int wave = threadIdx.x >> 6, lane = threadIdx.x & 63;
    if (lane == 0) { sred[wave] = x; sred[4 + wave] = y; }
    __syncthreads();
    x = sred[0] + sred[1] + sred[2] + sred[3];
    y = sred[4] + sred[5] + sred[6] + sred[7];
    __syncthreads();
}

// ---------------- tiny prep kernels ----------------
__global__ void __launch_bounds__(256) cls_max_k(
    const float* __restrict__ pc, const float* __restrict__ ic,
    float* __restrict__ pcls, float* __restrict__ icls) {
    const int g = blockIdx.x * 256 + threadIdx.x;  // 4096
    const int b = g >> 11, n = g & 2047;
    float m1 = -1e30f, m2 = -1e30f;
    #pragma unroll
    for (int k = 0; k < 10; ++k) {
        const float v1 = pc[((size_t)b * 10 + k) * N2 + n];
        const float v2 = ic[((size_t)b * 10 + k) * N2 + n];
        m1 = fmaxf(m1, 1.f / (1.f + __expf(-v1)));
        m2 = fmaxf(m2, 1.f / (1.f + __expf(-v2)));
    }
    pcls[g] = m1; icls[g] = m2;
}

__global__ void __launch_bounds__(256) transpose_k(
    const float* __restrict__ in, float* __restrict__ out, int R, int C) {
    __shared__ float t[32][33];
    const int nct = C >> 5;
    const int bx = blockIdx.x % nct, by = blockIdx.x / nct;
    const int c0 = bx * 32, r0 = by * 32;
    const int tx = threadIdx.x & 31, ty = threadIdx.x >> 5;
    #pragma unroll
    for (int i = 0; i < 4; ++i) {
        const int r = ty + i * 8;
        t[r][tx] = in[(size_t)(r0 + r) * C + c0 + tx];
    }
    __syncthreads();
    #pragma unroll
    for (int i = 0; i < 4; ++i) {
        const int r = ty + i * 8;
        out[(size_t)(c0 + r) * R + r0 + tx] = t[tx][r];
    }
}

// proj + pos-embed
__global__ void __launch_bounds__(256) proj_rows(
    const float* __restrict__ F, const float* __restrict__ WT,
    const float* __restrict__ bias, const float* __restrict__ Wpos,
    const float* __restrict__ bpos, const float* __restrict__ pos,
    float* __restrict__ outb) {
    const int b = blockIdx.x >> 8;
    const int n0 = (blockIdx.x & 255) * 8;
    const int tid = threadIdx.x;
    __shared__ float s_x[8][256];
    for (int idx = tid; idx < 2048; idx += 256) {
        const int r = idx & 7, c = idx >> 3;
        s_x[r][c] = F[((size_t)b * CH + c) * N2 + n0 + r];
    }
    __syncthreads();
    float acc[8] = {0, 0, 0, 0, 0, 0, 0, 0};
    for (int c = 0; c < 256; ++c) {
        const float w = WT[(size_t)c * CH + tid];
        #pragma unroll
        for (int r = 0; r < 8; ++r) acc[r] += s_x[r][c] * w;
    }
    const float badd = bias[tid] + bpos[tid];
    const float w0 = Wpos[tid * 2 + 0], w1 = Wpos[tid * 2 + 1];
    #pragma unroll
    for (int r = 0; r < 8; ++r) {
        const int n = n0 + r;
        const float p0 = pos[((size_t)b * N2 + n) * 2 + 0];
        const float p1 = pos[((size_t)b * N2 + n) * 2 + 1];
        outb[((size_t)b * N2 + n) * CH + tid] = acc[r] + badd + w0 * p0 + w1 * p1;
    }
}

// ---------------- IPOT as regular kernels (no cooperative launch) ----------------
// Decomposition: grid 512 = 2 batches x 256 blocks x 8 rows. Thread t owns
// cols {4t..4t+3} u {1024+4t..1024+4t+3} of its block's rows.

__device__ __forceinline__ void load_cols(const float* ipos, int batch, int tid,
                                          float* ixr, float* iyr) {
    const float4* ip4 = (const float4*)(ipos + (size_t)batch * (N2 * 2));
    const float4 A = ip4[tid * 2], B = ip4[tid * 2 + 1];
    const float4 Cc = ip4[512 + tid * 2], D = ip4[512 + tid * 2 + 1];
    ixr[0] = A.x; iyr[0] = A.y; ixr[1] = A.z; iyr[1] = A.w;
    ixr[2] = B.x; iyr[2] = B.y; ixr[3] = B.z; iyr[3] = B.w;
    ixr[4] = Cc.x; iyr[4] = Cc.y; ixr[5] = Cc.z; iyr[5] = Cc.w;
    ixr[6] = D.x; iyr[6] = D.y; ixr[7] = D.z; iyr[7] = D.w;
}

// init: Q1 = max(G,1e-6); a1 = pcls/(rowsum/2048+1e-6) -> avec; cs partials -> cpart
__global__ void __launch_bounds__(256) ipot_init_k(
    float* __restrict__ Q, const float* __restrict__ ppos, const float* __restrict__ ipos,
    const float* __restrict__ pcls, float* __restrict__ avec, float* __restrict__ cpart) {
    const int blk = blockIdx.x;
    const int batch = blk >> 8;
    const int p = blk & 255;
    const int r0 = p * 8;
    const int tid = threadIdx.x, wave = tid >> 6, lane = tid & 63;
    __shared__ float s_tot[4][8];

    float ixr[8], iyr[8];
    load_cols(ipos, batch, tid, ixr, iyr);
    float px[8], py[8], pcl8[8];
    #pragma unroll
    for (int j = 0; j < 8; ++j) {
        px[j] = ppos[((size_t)batch * N2 + r0 + j) * 2 + 0];
        py[j] = ppos[((size_t)batch * N2 + r0 + j) * 2 + 1];
        pcl8[j] = pcls[batch * N2 + r0 + j];
    }
    float* Qb = Q + (size_t)batch * N2 * N2;
    float cs[8] = {0, 0, 0, 0, 0, 0, 0, 0};

    #pragma unroll
    for (int h = 0; h < 2; ++h) {
        float qn[4][8];
        float rd[4];
        #pragma unroll
        for (int jj = 0; jj < 4; ++jj) {
            const int j = 4 * h + jj;
            rd[jj] = 0.f;
            #pragma unroll
            for (int k = 0; k < 8; ++k) {
                const float dx = px[j] - ixr[k], dy = py[j] - iyr[k];
                qn[jj][k] = fmaxf(__expf(-0.1f * sqrtf(dx * dx + dy * dy)), 1e-6f);
                rd[jj] += qn[jj][k];
            }
            float4* row4 = (float4*)(Qb + (size_t)(r0 + j) * N2);
            float4 lo, hi;
            lo.x = qn[jj][0]; lo.y = qn[jj][1]; lo.z = qn[jj][2]; lo.w = qn[jj][3];
            hi.x = qn[jj][4]; hi.y = qn[jj][5]; hi.z = qn[jj][6]; hi.w = qn[jj][7];
            row4[tid] = lo; row4[256 + tid] = hi;
        }
        #pragma unroll
        for (int off = 32; off; off >>= 1) {
            #pragma unroll
            for (int jj = 0; jj < 4; ++jj) rd[jj] += __shfl_xor(rd[jj], off);
        }
        if (lane == 0) {
            #pragma unroll
            for (int jj = 0; jj < 4; ++jj) s_tot[wave][4 * h + jj] = rd[jj];
        }
        __syncthreads();
        #pragma unroll
        for (int jj = 0; jj < 4; ++jj) {
            const int j = 4 * h + jj;
            const float tot = s_tot[0][j] + s_tot[1][j] + s_tot[2][j] + s_tot[3][j];
            const float a = pcl8[j] / (tot * (1.f / 2048.f) + 1e-6f);
            if (tid == 0) avec[batch * N2 + r0 + j] = a;
            #pragma unroll
            for (int k = 0; k < 8; ++k) cs[k] += a * qn[jj][k];
        }
    }
    float4* cp4 = (float4*)(cpart + ((size_t)batch * 256 + p) * N2);
    float4 l, h4;
    l.x = cs[0]; l.y = cs[1]; l.z = cs[2]; l.w = cs[3];
    h4.x = cs[4]; h4.y = cs[5]; h4.z = cs[6]; h4.w = cs[7];
    cp4[tid] = l; cp4[256 + tid] = h4;
}

// reduce: bvec = icls / (colsum of cpart + 1e-6). grid 64 = 2 batches x 32 col-tiles(64).
__global__ void __launch_bounds__(256) ipot_red_k(
    const float* __restrict__ cpart, const float* __restrict__ icls,
    float* __restrict__ bvec) {
    const int b = blockIdx.x >> 5;
    const int c0 = (blockIdx.x & 31) * 64;
    const int tid = threadIdx.x;
    const int c = tid & 63, pg = tid >> 6;   // 4 partial groups
    __shared__ float s_part[4][64];
    const float* cpb = cpart + (size_t)b * 256 * N2 + c0 + c;
    float s = 0.f;
    #pragma unroll 8
    for (int k = 0; k < 64; ++k) s += cpb[(size_t)(pg + 4 * k) * N2];
    s_part[pg][c] = s;
    __syncthreads();
    if (tid < 64) {
        const float tot = s_part[0][tid] + s_part[1][tid] + s_part[2][tid] + s_part[3][tid];
        bvec[b * N2 + c0 + tid] = icls[b * N2 + c0 + tid] / (tot + 1e-6f);
    }
}

// one iteration: Q <- max(G*(a*Q*b),1e-6); a <- pcls/(Q.b+1e-6); cs partials -> cpart
__global__ void __launch_bounds__(256) ipot_ur_k(
    float* __restrict__ Q, const float* __restrict__ ppos, const float* __restrict__ ipos,
    const float* __restrict__ pcls, const float* __restrict__ bvec,
    float* __restrict__ avec, float* __restrict__ cpart) {
    const int blk = blockIdx.x;
    const int batch = blk >> 8;
    const int p = blk & 255;
    const int r0 = p * 8;
    const int tid = threadIdx.x, wave = tid >> 6, lane = tid & 63;
    __shared__ float s_tot[4][8];

    float ixr[8], iyr[8];
    load_cols(ipos, batch, tid, ixr, iyr);
    float bb[8];
    {
        const float4* bv4 = (const float4*)(bvec + (size_t)batch * N2);
        const float4 l = bv4[tid], h4 = bv4[256 + tid];
        bb[0] = l.x; bb[1] = l.y; bb[2] = l.z; bb[3] = l.w;
        bb[4] = h4.x; bb[5] = h4.y; bb[6] = h4.z; bb[7] = h4.w;
    }
    float px[8], py[8], pcl8[8], a_cur[8];
    #pragma unroll
    for (int j = 0; j < 8; ++j) {
        px[j] = ppos[((size_t)batch * N2 + r0 + j) * 2 + 0];
        py[j] = ppos[((size_t)batch * N2 + r0 + j) * 2 + 1];
        pcl8[j] = pcls[batch * N2 + r0 + j];
        a_cur[j] = avec[batch * N2 + r0 + j];
    }
    float* Qb = Q + (size_t)batch * N2 * N2;
    float cs[8] = {0, 0, 0, 0, 0, 0, 0, 0};

    #pragma unroll
    for (int h = 0; h < 2; ++h) {
        float qn[4][8];
        float rd[4];
        #pragma unroll
        for (int jj = 0; jj < 4; ++jj) {
            const int j = 4 * h + jj;
            float4* row4 = (float4*)(Qb + (size_t)(r0 + j) * N2);
            const float4 lo = row4[tid], hi = row4[256 + tid];
            float qv[8];
            qv[0] = lo.x; qv[1] = lo.y; qv[2] = lo.z; qv[3] = lo.w;
            qv[4] = hi.x; qv[5] = hi.y; qv[6] = hi.z; qv[7] = hi.w;
            rd[jj] = 0.f;
            const float a = a_cur[j];
            #pragma unroll
            for (int k = 0; k < 8; ++k) {
                const float dx = px[j] - ixr[k], dy = py[j] - iyr[k];
                const float G = __expf(-0.1f * sqrtf(dx * dx + dy * dy));
                const float v = fmaxf(G * ((a * qv[k]) * bb[k]), 1e-6f);
                qn[jj][k] = v;
                rd[jj] += v * bb[k];
            }
            float4 lo2, hi2;
            lo2.x = qn[jj][0]; lo2.y = qn[jj][1]; lo2.z = qn[jj][2]; lo2.w = qn[jj][3];
            hi2.x = qn[jj][4]; hi2.y = qn[jj][5]; hi2.z = qn[jj][6]; hi2.w = qn[jj][7];
            row4[tid] = lo2; row4[256 + tid] = hi2;
        }
        #pragma unroll
        for (int off = 32; off; off >>= 1) {
            #pragma unroll
            for (int jj = 0; jj < 4; ++jj) rd[jj] += __shfl_xor(rd[jj], off);
        }
        if (lane == 0) {
            #pragma unroll
            for (int jj = 0; jj < 4; ++jj) s_tot[wave][4 * h + jj] = rd[jj];
        }
        __syncthreads();
        #pragma unroll
        for (int jj = 0; jj < 4; ++jj) {
            const int j = 4 * h + jj;
            const float tot = s_tot[0][j] + s_tot[1][j] + s_tot[2][j] + s_tot[3][j];
            const float a = pcl8[j] / (tot + 1e-6f);
            if (tid == 0) avec[batch * N2 + r0 + j] = a;
            #pragma unroll
            for (int k = 0; k < 8; ++k) cs[k] += a * qn[jj][k];
        }
    }
    float4* cp4 = (float4*)(cpart + ((size_t)batch * 256 + p) * N2);
    float4 l, h4;
    l.x = cs[0]; l.y = cs[1]; l.z = cs[2]; l.w = cs[3];
    h4.x = cs[4]; h4.y = cs[5]; h4.z = cs[6]; h4.w = cs[7];
    cp4[tid] = l; cp4[256 + tid] = h4;
}

// final: res = a*Q*b, row-L1-normalize, write into Q
__global__ void __launch_bounds__(256) ipot_fin_k(
    float* __restrict__ Q, const float* __restrict__ pcls,
    const float* __restrict__ bvec, const float* __restrict__ avec) {
    const int blk = blockIdx.x;
    const int batch = blk >> 8;
    const int p = blk & 255;
    const int r0 = p * 8;
    const int tid = threadIdx.x, wave = tid >> 6, lane = tid & 63;
    __shared__ float s_tot[4][8];

    float bb[8];
    {
        const float4* bv4 = (const float4*)(bvec + (size_t)batch * N2);
        const float4 l = bv4[tid], h4 = bv4[256 + tid];
        bb[0] = l.x; bb[1] = l.y; bb[2] = l.z; bb[3] = l.w;
        bb[4] = h4.x; bb[5] = h4.y; bb[6] = h4.z; bb[7] = h4.w;
    }
    float a8[8];
    #pragma unroll
    for (int j = 0; j < 8; ++j) a8[j] = avec[batch * N2 + r0 + j];
    float* Qb = Q + (size_t)batch * N2 * N2;

    #pragma unroll
    for (int h = 0; h < 2; ++h) {
        float vv[4][8];
        float rs[4];
        #pragma unroll
        for (int jj = 0; jj < 4; ++jj) {
            const int j = 4 * h + jj;
            float4* row4 = (float4*)(Qb + (size_t)(r0 + j) * N2);
            const float4 lo = row4[tid], hi = row4[256 + tid];
            float qv[8];
            qv[0] = lo.x; qv[1] = lo.y; qv[2] = lo.z; qv[3] = lo.w;
            qv[4] = hi.x; qv[5] = hi.y; qv[6] = hi.z; qv[7] = hi.w;
            rs[jj] = 0.f;
            const float a = a8[j];
            #pragma unroll
            for (int k = 0; k < 8; ++k) {
                const float v = (a * qv[k]) * bb[k];
                vv[jj][k] = v;
                rs[jj] += v;
            }
        }
        #pragma unroll
        for (int off = 32; off; off >>= 1) {
            #pragma unroll
            for (int jj = 0; jj < 4; ++jj) rs[jj] += __shfl_xor(rs[jj], off);
        }
        if (lane == 0) {
            #pragma unroll
            for (int jj = 0; jj < 4; ++jj) s_tot[wave][4 * h + jj] = rs[jj];
        }
        __syncthreads();
        #pragma unroll
        for (int jj = 0; jj < 4; ++jj) {
            const int j = 4 * h + jj;
            const float tot = s_tot[0][j] + s_tot[1][j] + s_tot[2][j] + s_tot[3][j];
            const float sc = 1.f / fmaxf(tot, 1e-12f);
            float4* row4 = (float4*)(Qb + (size_t)(r0 + j) * N2);
            float4 lo, hi;
            lo.x = vv[jj][0] * sc; lo.y = vv[jj][1] * sc;
            lo.z = vv[jj][2] * sc; lo.w = vv[jj][3] * sc;
            hi.x = vv[jj][4] * sc; hi.y = vv[jj][5] * sc;
            hi.z = vv[jj][6] * sc; hi.w = vv[jj][7] * sc;
            row4[tid] = lo; row4[256 + tid] = hi;
        }
    }
}

// ---------------- att GEMM: att[b][n][c] = sum_m res~[b][n][m] * imfT[b][m][c]
__global__ void __launch_bounds__(256) att_gemm(
    const float* __restrict__ R, const float* __restrict__ V, float* __restrict__ att) {
    const int bid = blockIdx.x;               // 2*32*4 = 256
    const int nt = bid & 31, ct = (bid >> 5) & 3, b = bid >> 7;
    const int n0 = nt * 64, c0 = ct * 64;
    __shared__ float sR[64][17];
    __shared__ float sV[16][65];
    const int tid = threadIdx.x;
    const int cx = tid & 15, ny = tid >> 4;
    float acc[4][4] = {};
    const float* Rb = R + (size_t)b * N2 * N2;
    const float* Vb = V + (size_t)b * N2 * CH;
    for (int k0 = 0; k0 < N2; k0 += 16) {
        for (int idx = tid; idx < 1024; idx += 256) {
            const int nl = idx >> 4, kk = idx & 15;
            sR[nl][kk] = Rb[(size_t)(n0 + nl) * N2 + k0 + kk];
        }
        for (int idx = tid; idx < 1024; idx += 256) {
            const int kk = idx >> 6, cl = idx & 63;
            sV[kk][cl] = Vb[(size_t)(k0 + kk) * CH + c0 + cl];
        }
        __syncthreads();
        #pragma unroll
        for (int kk = 0; kk < 16; ++kk) {
            float av[4], bv[4];
            #pragma unroll
            for (int i = 0; i < 4; ++i) av[i] = sR[ny + 16 * i][kk];
            #pragma unroll
            for (int j = 0; j < 4; ++j) bv[j] = sV[kk][cx + 16 * j];
            #pragma unroll
            for (int i = 0; i < 4; ++i)
                #pragma unroll
                for (int j = 0; j < 4; ++j) acc[i][j] += av[i] * bv[j];
        }
        __syncthreads();
    }
    #pragma unroll
    for (int i = 0; i < 4; ++i)
        #pragma unroll
        for (int j = 0; j < 4; ++j)
            att[((size_t)b * N2 + n0 + ny + 16 * i) * CH + c0 + cx + 16 * j] = acc[i][j];
}

// ---------------- out_projection + LN ----------------
__global__ void __launch_bounds__(256) outproj_k(
    const float* __restrict__ pf, const float* __restrict__ att,
    const float* __restrict__ WoutT,
    const float* __restrict__ bout, const float* __restrict__ g,
    const float* __restrict__ be, float* __restrict__ y) {
    const int b = blockIdx.x >> 8;
    const int n0 = (blockIdx.x & 255) * 8;
    const int tid = threadIdx.x;
    __shared__ float s_x[8][512];
    __shared__ float sred[8];
    for (int idx = tid; idx < 2048; idx += 256) {
        const int k = idx & 255, r = idx >> 8;
        s_x[r][k] = pf[((size_t)b * N2 + n0 + r) * CH + k];
        s_x[r][256 + k] = att[((size_t)b * N2 + n0 + r) * CH + k];
    }
    __syncthreads();
    float acc[8] = {0, 0, 0, 0, 0, 0, 0, 0};
    for (int k = 0; k < 512; ++k) {
        const float w = WoutT[(size_t)k * CH + tid];
        #pragma unroll
        for (int r = 0; r < 8; ++r) acc[r] += s_x[r][k] * w;
    }
    const float bo = bout[tid], gg = g[tid], bb = be[tid];
    #pragma unroll
    for (int r = 0; r < 8; ++r) {
        const float v = acc[r] + bo;
        float s1 = v, s2 = v * v;
        blockReduce2(s1, s2, sred);
        const float mu = s1 * (1.f / 256.f);
        const float var = s2 * (1.f / 256.f) - mu * mu;
        y[((size_t)b * N2 + n0 + r) * CH + tid] = (v - mu) * rsqrtf(var + 1e-5f) * gg + bb;
    }
}

// ---------------- fused FFN + residual + LN + pred head ----------------
__global__ void __launch_bounds__(256) ffn_k(
    const float* __restrict__ y, const float* __restrict__ Wf1T,
    const float* __restrict__ bf1, const float* __restrict__ Wf2T,
    const float* __restrict__ bf2, const float* __restrict__ gln,
    const float* __restrict__ bln, const float* __restrict__ Wpred,
    const float* __restrict__ bpred, const float* __restrict__ pos,
    float* __restrict__ y2, float* __restrict__ out1,
    float* __restrict__ out2) {
    const int b = blockIdx.x >> 8;
    const int n0 = (blockIdx.x & 255) * 8;
    const int tid = threadIdx.x;
    __shared__ float s_y[8][256];
    __shared__ float s_h[8][1024];
    __shared__ float sred[8];
    for (int idx = tid; idx < 2048; idx += 256) {
        const int c = idx & 255, r = idx >> 8;
        s_y[r][c] = y[((size_t)b * N2 + n0 + r) * CH + c];
    }
    __syncthreads();
    float acc[4][8] = {};
    for (int c = 0; c < 256; ++c) {
        float yv[8];
        #pragma unroll
        for (int r = 0; r < 8; ++r) yv[r] = s_y[r][c];
        #pragma unroll
        for (int fi = 0; fi < 4; ++fi) {
            const float w = Wf1T[(size_t)c * FFNC + fi * 256 + tid];
            #pragma unroll
            for (int r = 0; r < 8; ++r) acc[fi][r] += yv[r] * w;
        }
    }
    #pragma unroll
    for (int fi = 0; fi < 4; ++fi) {
        const int f = fi * 256 + tid;
        const float bb = bf1[f];
        #pragma unroll
        for (int r = 0; r < 8; ++r) s_h[r][f] = fmaxf(acc[fi][r] + bb, 0.f);
    }
    __syncthreads();
    float a2[8] = {0, 0, 0, 0, 0, 0, 0, 0};
    for (int f = 0; f < 1024; ++f) {
        const float w = Wf2T[(size_t)f * CH + tid];
        #pragma unroll
        for (int r = 0; r < 8; ++r) a2[r] += s_h[r][f] * w;
    }
    const float bfv = bf2[tid], gg = gln[tid], bb2 = bln[tid];
    const float wp0 = Wpred[tid], wp1 = Wpred[CH + tid];
    #pragma unroll
    for (int r = 0; r < 8; ++r) {
        const int n = n0 + r;
        const float v = a2[r] + bfv + s_y[r][tid];
        float s1 = v, s2 = v * v;
        blockReduce2(s1, s2, sred);
        const float mu = s1 * (1.f / 256.f);
        const float var = s2 * (1.f / 256.f) - mu * mu;
        const float xo = (v - mu) * rsqrtf(var + 1e-5f) * gg + bb2;
        y2[((size_t)b * N2 + n) * CH + tid] = xo;
        float d0 = wp0 * xo, d1 = wp1 * xo;
        blockReduce2(d0, d1, sred);
        if (tid == 0) {
            const float c0v = d0 + bpred[0] + pos[((size_t)b * N2 + n) * 2 + 0];
            const float c1v = d1 + bpred[1] + pos[((size_t)b * N2 + n) * 2 + 1];
            out2[((size_t)b * 2 + 0) * N2 + n] = c0v;
            out2[((size_t)b * 2 + 1) * N2 + n] = c1v;
            out1[((size_t)b * N2 + n) * 2 + 0] = c0v;
            out1[((size_t)b * N2 + n) * 2 + 1] = c1v;
        }
    }
}

// ---------------- transpose xo -> out0 [b][c][n] f32 ----------------
__global__ void __launch_bounds__(256) out_x_k(
    const float* __restrict__ y2, float* __restrict__ out0) {
    __shared__ float t[32][33];
    const int bid = blockIdx.x;                      // 2*64*8 = 1024
    const int ct = bid & 7, nt = (bid >> 3) & 63, b = bid >> 9;
    const int tx = threadIdx.x & 31, ty = threadIdx.x >> 5;
    #pragma unroll
    for (int i = 0; i < 4; ++i) {
        const int r = ty + i * 8;
        t[r][tx] = y2[((size_t)b * N2 + nt * 32 + r) * CH + ct * 32 + tx];
    }
    __syncthreads();
    #pragma unroll
    for (int i = 0; i < 4; ++i) {
        const int r = ty + i * 8;
        out0[((size_t)b * CH + ct * 32 + r) * N2 + nt * 32 + tx] = t[tx][r];
    }
}

// ---------------- launcher ----------------
extern "C" void kernel_launch(void* const* d_in, const int* in_sizes, int n_in,
                              void* d_out, int out_size, void* d_ws, size_t ws_size,
                              hipStream_t stream) {
    const float* ptsf  = (const float*)d_in[0];
    const float* ppos  = (const float*)d_in[1];
    const float* imgf  = (const float*)d_in[2];
    const float* ipos  = (const float*)d_in[3];
    const float* pcin  = (const float*)d_in[4];
    const float* icin  = (const float*)d_in[5];
    const float* Wp    = (const float*)d_in[6];
    const float* bp    = (const float*)d_in[7];
    const float* Wi    = (const float*)d_in[8];
    const float* bi    = (const float*)d_in[9];
    const float* Wqp   = (const float*)d_in[10];
    const float* bqp   = (const float*)d_in[11];
    const float* Wkp   = (const float*)d_in[12];
    const float* bkp   = (const float*)d_in[13];
    const float* Wout  = (const float*)d_in[14];
    const float* bout  = (const float*)d_in[15];
    const float* gout  = (const float*)d_in[16];
    const float* beo   = (const float*)d_in[17];
    const float* Wf1   = (const float*)d_in[18];
    const float* bf1   = (const float*)d_in[19];
    const float* Wf2   = (const float*)d_in[20];
    const float* bf2   = (const float*)d_in[21];
    const float* gln   = (const float*)d_in[22];
    const float* bln   = (const float*)d_in[23];
    const float* Wpred = (const float*)d_in[24];
    const float* bpred = (const float*)d_in[25];

    float* ws    = (float*)d_ws;
    float* Q     = ws + OFF_Q;
    float* imfT  = ws + OFF_IMFT;
    float* pf    = ws + OFF_PF;
    float* cpart = ws + OFF_CPART;
    float* att   = ws + OFF_CPART;   // alias: cpart dead after ipot
    float* WpT   = ws + OFF_CPART;   // alias: dead before ipot writes cpart
    float* WiT   = ws + OFF_CPART + 65536u;
    float* pcls  = ws + OFF_PCLS;
    float* icls  = ws + OFF_ICLS;
    float* bvec  = ws + OFF_BVEC;
    float* avec  = ws + OFF_AVEC;
    float* WoutT = ws + OFF_WOUTT;
    float* Wf1T  = ws + OFF_WF1T;
    float* Wf2T  = ws + OFF_WF2T;
    float* yb    = ws + OFF_Q;       // alias: Q dead after att_gemm
    float* y2    = ws + OFF_PF;      // alias: pf dead after outproj

    float* out0 = (float*)d_out;                     // x       [2,256,2048]
    float* out1 = out0 + (size_t)2 * CH * N2;        // new_pos [2,2048,2]
    float* out2 = out1 + (size_t)2 * N2 * 2;         // center  [2,2,2048]

    cls_max_k<<<16, 256, 0, stream>>>(pcin, icin, pcls, icls);
    transpose_k<<<64, 256, 0, stream>>>(Wp, WpT, 256, 256);
    transpose_k<<<64, 256, 0, stream>>>(Wi, WiT, 256, 256);
    transpose_k<<<128, 256, 0, stream>>>(Wout, WoutT, 256, 512);
    transpose_k<<<256, 256, 0, stream>>>(Wf1, Wf1T, 1024, 256);
    transpose_k<<<256, 256, 0, stream>>>(Wf2, Wf2T, 256, 1024);
    proj_rows<<<512, 256, 0, stream>>>(ptsf, WpT, bp, Wqp, bqp, ppos, pf);
    proj_rows<<<512, 256, 0, stream>>>(imgf, WiT, bi, Wkp, bkp, ipos, imfT);

    // IPOT: 100 iterations, kernel-boundary synchronization (no cooperative launch)
    ipot_init_k<<<512, 256, 0, stream>>>(Q, ppos, ipos, pcls, avec, cpart);
    for (int t = 1; t < 100; ++t) {
        ipot_red_k<<<64, 256, 0, stream>>>(cpart, icls, bvec);
        ipot_ur_k<<<512, 256, 0, stream>>>(Q, ppos, ipos, pcls, bvec, avec, cpart);
    }
    ipot_red_k<<<64, 256, 0, stream>>>(cpart, icls, bvec);
    ipot_fin_k<<<512, 256, 0, stream>>>(Q, pcls, bvec, avec);

    att_gemm<<<256, 256, 0, stream>>>(Q, imfT, att);
    outproj_k<<<512, 256, 0, stream>>>(pf, att, WoutT, bout, gout, beo, yb);
    ffn_k<<<512, 256, 0, stream>>>(yb, Wf1T, bf1, Wf2T, bf2, gln, bln,
                                   Wpred, bpred, ppos, y2, out1, out2);
    out_x_k<<<1024, 256, 0, stream>>>(y2, out0);
}

// Round 7
// 2607.641 us; speedup vs baseline: 5.5431x; 1.0142x over previous
//
#include <hip/hip_runtime.h>
#include <hip/hip_bf16.h>

#define N2   2048
#define CH   256
#define FFNC 1024

// ---------------- workspace layout (float offsets), total 48.8MB (proven) ----------------
#define OFF_Q      0u                        // [2][2048][2048]; post-att_gemm: pf/yb/y2/WpT live here
#define OFF_IMFT   8388608u                  // [2][2048][256]
#define OFF_CPART  9437184u                  // [2][512][2048] colsum partials; WiT pre-ipot, att after
#define OFF_PCLS   11534336u                 // [2][2048]
#define OFF_ICLS   11538432u
#define OFF_BVEC   11542528u
#define OFF_AVEC   11546624u
#define OFF_WOUTT  11550720u                 // [512][256]
#define OFF_WF1T   11681792u                 // [256][1024]
#define OFF_WF2T   11943936u                 // [1024][256]  end = 12206080 floats = 48.8MB

// ---------------- helpers ----------------
__device__ __forceinline__ void blockReduce2(float& x, float& y, float* sred) {
    #pragma unroll
    for (int off = 32; off; off >>= 1) {
        x += __shfl_xor(x, off);
        y += __shfl_xor(y, off);
    }
    const int wave = threadIdx.x >> 6, lane = threadIdx.x & 63;
    if (lane == 0) { sred[wave] = x; sred[4 + wave] = y; }
    __syncthreads();
    x = sred[0] + sred[1] + sred[2] + sred[3];
    y = sred[4] + sred[5] + sred[6] + sred[7];
    __syncthreads();
}

// ---------------- tiny prep kernels ----------------
__global__ void __launch_bounds__(256) cls_max_k(
    const float* __restrict__ pc, const float* __restrict__ ic,
    float* __restrict__ pcls, float* __restrict__ icls) {
    const int g = blockIdx.x * 256 + threadIdx.x;  // 4096
    const int b = g >> 11, n = g & 2047;
    float m1 = -1e30f, m2 = -1e30f;
    #pragma unroll
    for (int k = 0; k < 10; ++k) {
        const float v1 = pc[((size_t)b * 10 + k) * N2 + n];
        const float v2 = ic[((size_t)b * 10 + k) * N2 + n];
        m1 = fmaxf(m1, 1.f / (1.f + __expf(-v1)));
        m2 = fmaxf(m2, 1.f / (1.f + __expf(-v2)));
    }
    pcls[g] = m1; icls[g] = m2;
}

__global__ void __launch_bounds__(256) transpose_k(
    const float* __restrict__ in, float* __restrict__ out, int R, int C) {
    __shared__ float t[32][33];
    const int nct = C >> 5;
    const int bx = blockIdx.x % nct, by = blockIdx.x / nct;
    const int c0 = bx * 32, r0 = by * 32;
    const int tx = threadIdx.x & 31, ty = threadIdx.x >> 5;
    #pragma unroll
    for (int i = 0; i < 4; ++i) {
        const int r = ty + i * 8;
        t[r][tx] = in[(size_t)(r0 + r) * C + c0 + tx];
    }
    __syncthreads();
    #pragma unroll
    for (int i = 0; i < 4; ++i) {
        const int r = ty + i * 8;
        out[(size_t)(c0 + r) * R + r0 + tx] = t[tx][r];
    }
}

// proj + pos-embed
__global__ void __launch_bounds__(256) proj_rows(
    const float* __restrict__ F, const float* __restrict__ WT,
    const float* __restrict__ bias, const float* __restrict__ Wpos,
    const float* __restrict__ bpos, const float* __restrict__ pos,
    float* __restrict__ outb) {
    const int b = blockIdx.x >> 8;
    const int n0 = (blockIdx.x & 255) * 8;
    const int tid = threadIdx.x;
    __shared__ float s_x[8][256];
    for (int idx = tid; idx < 2048; idx += 256) {
        const int r = idx & 7, c = idx >> 3;
        s_x[r][c] = F[((size_t)b * CH + c) * N2 + n0 + r];
    }
    __syncthreads();
    float acc[8] = {0, 0, 0, 0, 0, 0, 0, 0};
    for (int c = 0; c < 256; ++c) {
        const float w = WT[(size_t)c * CH + tid];
        #pragma unroll
        for (int r = 0; r < 8; ++r) acc[r] += s_x[r][c] * w;
    }
    const float badd = bias[tid] + bpos[tid];
    const float w0 = Wpos[tid * 2 + 0], w1 = Wpos[tid * 2 + 1];
    #pragma unroll
    for (int r = 0; r < 8; ++r) {
        const int n = n0 + r;
        const float p0 = pos[((size_t)b * N2 + n) * 2 + 0];
        const float p1 = pos[((size_t)b * N2 + n) * 2 + 1];
        outb[((size_t)b * N2 + n) * CH + tid] = acc[r] + badd + w0 * p0 + w1 * p1;
    }
}

// ---------------- IPOT (regular kernels, 4 rows/block, grid 1024) ----------------
// Thread t owns cols {4t..4t+3} u {1024+4t..1024+4t+3} of its block's 4 rows.

__device__ __forceinline__ void load_cols(const float* ipos, int batch, int tid,
                                          float* ixr, float* iyr) {
    const float4* ip4 = (const float4*)(ipos + (size_t)batch * (N2 * 2));
    const float4 A = ip4[tid * 2], B = ip4[tid * 2 + 1];
    const float4 Cc = ip4[512 + tid * 2], D = ip4[512 + tid * 2 + 1];
    ixr[0] = A.x; iyr[0] = A.y; ixr[1] = A.z; iyr[1] = A.w;
    ixr[2] = B.x; iyr[2] = B.y; ixr[3] = B.z; iyr[3] = B.w;
    ixr[4] = Cc.x; iyr[4] = Cc.y; ixr[5] = Cc.z; iyr[5] = Cc.w;
    ixr[6] = D.x; iyr[6] = D.y; ixr[7] = D.z; iyr[7] = D.w;
}

// init: Q1 = max(G,1e-6); a1 = pcls/(rowsum/2048+1e-6) -> avec; cs partials -> cpart
__global__ void __launch_bounds__(256, 4) ipot_init_k(
    float* __restrict__ Q, const float* __restrict__ ppos, const float* __restrict__ ipos,
    const float* __restrict__ pcls, float* __restrict__ avec, float* __restrict__ cpart) {
    const int blk = blockIdx.x;
    const int batch = blk >> 9;
    const int p = blk & 511;
    const int r0 = p * 4;
    const int tid = threadIdx.x, wave = tid >> 6, lane = tid & 63;
    __shared__ float s_tot[4][4];

    float ixr[8], iyr[8];
    load_cols(ipos, batch, tid, ixr, iyr);
    float px[4], py[4], pcl4[4];
    #pragma unroll
    for (int j = 0; j < 4; ++j) {
        px[j] = ppos[((size_t)batch * N2 + r0 + j) * 2 + 0];
        py[j] = ppos[((size_t)batch * N2 + r0 + j) * 2 + 1];
        pcl4[j] = pcls[batch * N2 + r0 + j];
    }
    float* Qb = Q + (size_t)batch * N2 * N2;
    float cs[8] = {0, 0, 0, 0, 0, 0, 0, 0};

    float qn[4][8];
    float rd[4];
    #pragma unroll
    for (int jj = 0; jj < 4; ++jj) {
        rd[jj] = 0.f;
        #pragma unroll
        for (int k = 0; k < 8; ++k) {
            const float dx = px[jj] - ixr[k], dy = py[jj] - iyr[k];
            qn[jj][k] = fmaxf(__expf(-0.1f * sqrtf(dx * dx + dy * dy)), 1e-6f);
            rd[jj] += qn[jj][k];
        }
        float4* row4 = (float4*)(Qb + (size_t)(r0 + jj) * N2);
        float4 lo, hi;
        lo.x = qn[jj][0]; lo.y = qn[jj][1]; lo.z = qn[jj][2]; lo.w = qn[jj][3];
        hi.x = qn[jj][4]; hi.y = qn[jj][5]; hi.z = qn[jj][6]; hi.w = qn[jj][7];
        row4[tid] = lo; row4[256 + tid] = hi;
    }
    #pragma unroll
    for (int off = 32; off; off >>= 1) {
        #pragma unroll
        for (int jj = 0; jj < 4; ++jj) rd[jj] += __shfl_xor(rd[jj], off);
    }
    if (lane == 0) {
        #pragma unroll
        for (int jj = 0; jj < 4; ++jj) s_tot[wave][jj] = rd[jj];
    }
    __syncthreads();
    #pragma unroll
    for (int jj = 0; jj < 4; ++jj) {
        const float tot = s_tot[0][jj] + s_tot[1][jj] + s_tot[2][jj] + s_tot[3][jj];
        const float a = pcl4[jj] / (tot * (1.f / 2048.f) + 1e-6f);
        if (tid == 0) avec[batch * N2 + r0 + jj] = a;
        #pragma unroll
        for (int k = 0; k < 8; ++k) cs[k] += a * qn[jj][k];
    }
    float4* cp4 = (float4*)(cpart + ((size_t)batch * 512 + p) * N2);
    float4 l, h4;
    l.x = cs[0]; l.y = cs[1]; l.z = cs[2]; l.w = cs[3];
    h4.x = cs[4]; h4.y = cs[5]; h4.z = cs[6]; h4.w = cs[7];
    cp4[tid] = l; cp4[256 + tid] = h4;
}

// reduce: bvec = icls / (colsum of 512 cpart partials + 1e-6). grid 64.
__global__ void __launch_bounds__(256) ipot_red_k(
    const float* __restrict__ cpart, const float* __restrict__ icls,
    float* __restrict__ bvec) {
    const int b = blockIdx.x >> 5;
    const int c0 = (blockIdx.x & 31) * 64;
    const int tid = threadIdx.x;
    const int c = tid & 63, pg = tid >> 6;   // 4 partial groups
    __shared__ float s_part[4][64];
    const float* cpb = cpart + (size_t)b * 512 * N2 + c0 + c;
    float s = 0.f;
    #pragma unroll 8
    for (int k = 0; k < 128; ++k) s += cpb[(size_t)(pg + 4 * k) * N2];
    s_part[pg][c] = s;
    __syncthreads();
    if (tid < 64) {
        const float tot = s_part[0][tid] + s_part[1][tid] + s_part[2][tid] + s_part[3][tid];
        bvec[b * N2 + c0 + tid] = icls[b * N2 + c0 + tid] / (tot + 1e-6f);
    }
}

// one iteration: Q <- max(G*(a*Q*b),1e-6); a <- pcls/(Q.b+1e-6); cs partials -> cpart
__global__ void __launch_bounds__(256, 4) ipot_ur_k(
    float* __restrict__ Q, const float* __restrict__ ppos, const float* __restrict__ ipos,
    const float* __restrict__ pcls, const float* __restrict__ bvec,
    float* __restrict__ avec, float* __restrict__ cpart) {
    const int blk = blockIdx.x;
    const int batch = blk >> 9;
    const int p = blk & 511;
    const int r0 = p * 4;
    const int tid = threadIdx.x, wave = tid >> 6, lane = tid & 63;
    __shared__ float s_tot[4][4];

    float ixr[8], iyr[8];
    load_cols(ipos, batch, tid, ixr, iyr);
    float bb[8];
    {
        const float4* bv4 = (const float4*)(bvec + (size_t)batch * N2);
        const float4 l = bv4[tid], h4 = bv4[256 + tid];
        bb[0] = l.x; bb[1] = l.y; bb[2] = l.z; bb[3] = l.w;
        bb[4] = h4.x; bb[5] = h4.y; bb[6] = h4.z; bb[7] = h4.w;
    }
    float px[4], py[4], pcl4[4], a_cur[4];
    #pragma unroll
    for (int j = 0; j < 4; ++j) {
        px[j] = ppos[((size_t)batch * N2 + r0 + j) * 2 + 0];
        py[j] = ppos[((size_t)batch * N2 + r0 + j) * 2 + 1];
        pcl4[j] = pcls[batch * N2 + r0 + j];
        a_cur[j] = avec[batch * N2 + r0 + j];
    }
    float* Qb = Q + (size_t)batch * N2 * N2;
    float cs[8] = {0, 0, 0, 0, 0, 0, 0, 0};

    float qn[4][8];
    float rd[4];
    #pragma unroll
    for (int jj = 0; jj < 4; ++jj) {
        float4* row4 = (float4*)(Qb + (size_t)(r0 + jj) * N2);
        const float4 lo = row4[tid], hi = row4[256 + tid];
        float qv[8];
        qv[0] = lo.x; qv[1] = lo.y; qv[2] = lo.z; qv[3] = lo.w;
        qv[4] = hi.x; qv[5] = hi.y; qv[6] = hi.z; qv[7] = hi.w;
        rd[jj] = 0.f;
        const float a = a_cur[jj];
        #pragma unroll
        for (int k = 0; k < 8; ++k) {
            const float dx = px[jj] - ixr[k], dy = py[jj] - iyr[k];
            const float G = __expf(-0.1f * sqrtf(dx * dx + dy * dy));
            const float v = fmaxf(G * ((a * qv[k]) * bb[k]), 1e-6f);
            qn[jj][k] = v;
            rd[jj] += v * bb[k];
        }
        float4 lo2, hi2;
        lo2.x = qn[jj][0]; lo2.y = qn[jj][1]; lo2.z = qn[jj][2]; lo2.w = qn[jj][3];
        hi2.x = qn[jj][4]; hi2.y = qn[jj][5]; hi2.z = qn[jj][6]; hi2.w = qn[jj][7];
        row4[tid] = lo2; row4[256 + tid] = hi2;
    }
    #pragma unroll
    for (int off = 32; off; off >>= 1) {
        #pragma unroll
        for (int jj = 0; jj < 4; ++jj) rd[jj] += __shfl_xor(rd[jj], off);
    }
    if (lane == 0) {
        #pragma unroll
        for (int jj = 0; jj < 4; ++jj) s_tot[wave][jj] = rd[jj];
    }
    __syncthreads();
    #pragma unroll
    for (int jj = 0; jj < 4; ++jj) {
        const float tot = s_tot[0][jj] + s_tot[1][jj] + s_tot[2][jj] + s_tot[3][jj];
        const float a = pcl4[jj] / (tot + 1e-6f);
        if (tid == 0) avec[batch * N2 + r0 + jj] = a;
        #pragma unroll
        for (int k = 0; k < 8; ++k) cs[k] += a * qn[jj][k];
    }
    float4* cp4 = (float4*)(cpart + ((size_t)batch * 512 + p) * N2);
    float4 l, h4;
    l.x = cs[0]; l.y = cs[1]; l.z = cs[2]; l.w = cs[3];
    h4.x = cs[4]; h4.y = cs[5]; h4.z = cs[6]; h4.w = cs[7];
    cp4[tid] = l; cp4[256 + tid] = h4;
}

// final: res = a*Q*b, row-L1-normalize, write into Q
__global__ void __launch_bounds__(256, 4) ipot_fin_k(
    float* __restrict__ Q, const float* __restrict__ pcls,
    const float* __restrict__ bvec, const float* __restrict__ avec) {
    const int blk = blockIdx.x;
    const int batch = blk >> 9;
    const int p = blk & 511;
    const int r0 = p * 4;
    const int tid = threadIdx.x, wave = tid >> 6, lane = tid & 63;
    __shared__ float s_tot[4][4];

    float bb[8];
    {
        const float4* bv4 = (const float4*)(bvec + (size_t)batch * N2);
        const float4 l = bv4[tid], h4 = bv4[256 + tid];
        bb[0] = l.x; bb[1] = l.y; bb[2] = l.z; bb[3] = l.w;
        bb[4] = h4.x; bb[5] = h4.y; bb[6] = h4.z; bb[7] = h4.w;
    }
    float a4[4];
    #pragma unroll
    for (int j = 0; j < 4; ++j) a4[j] = avec[batch * N2 + r0 + j];
    float* Qb = Q + (size_t)batch * N2 * N2;

    float vv[4][8];
    float rs[4];
    #pragma unroll
    for (int jj = 0; jj < 4; ++jj) {
        float4* row4 = (float4*)(Qb + (size_t)(r0 + jj) * N2);
        const float4 lo = row4[tid], hi = row4[256 + tid];
        float qv[8];
        qv[0] = lo.x; qv[1] = lo.y; qv[2] = lo.z; qv[3] = lo.w;
        qv[4] = hi.x; qv[5] = hi.y; qv[6] = hi.z; qv[7] = hi.w;
        rs[jj] = 0.f;
        const float a = a4[jj];
        #pragma unroll
        for (int k = 0; k < 8; ++k) {
            const float v = (a * qv[k]) * bb[k];
            vv[jj][k] = v;
            rs[jj] += v;
        }
    }
    #pragma unroll
    for (int off = 32; off; off >>= 1) {
        #pragma unroll
        for (int jj = 0; jj < 4; ++jj) rs[jj] += __shfl_xor(rs[jj], off);
    }
    if (lane == 0) {
        #pragma unroll
        for (int jj = 0; jj < 4; ++jj) s_tot[wave][jj] = rs[jj];
    }
    __syncthreads();
    #pragma unroll
    for (int jj = 0; jj < 4; ++jj) {
        const float tot = s_tot[0][jj] + s_tot[1][jj] + s_tot[2][jj] + s_tot[3][jj];
        const float sc = 1.f / fmaxf(tot, 1e-12f);
        float4* row4 = (float4*)(Qb + (size_t)(r0 + jj) * N2);
        float4 lo, hi;
        lo.x = vv[jj][0] * sc; lo.y = vv[jj][1] * sc;
        lo.z = vv[jj][2] * sc; lo.w = vv[jj][3] * sc;
        hi.x = vv[jj][4] * sc; hi.y = vv[jj][5] * sc;
        hi.z = vv[jj][6] * sc; hi.w = vv[jj][7] * sc;
        row4[tid] = lo; row4[256 + tid] = hi;
    }
}

// ---------------- att GEMM: att[b][n][c] = sum_m res~[b][n][m] * imfT[b][m][c]
__global__ void __launch_bounds__(256) att_zero_k(float* __restrict__ att) {
    const int idx = blockIdx.x * 256 + threadIdx.x;   // 262144 float4 = 1048576 floats
    float4 z; z.x = 0.f; z.y = 0.f; z.z = 0.f; z.w = 0.f;
    ((float4*)att)[idx] = z;
}

// grid 1024 = 2(b) x 4(ks) x 4(ct) x 32(nt). 64x64 tile, K-chunk 512, atomicAdd out.
// Inner loop: 2x ds_read_b128 + 16 FMA per k-step (transposed sRT).
__global__ void __launch_bounds__(256, 4) att_gemm(
    const float* __restrict__ R, const float* __restrict__ V, float* __restrict__ att) {
    const int bid = blockIdx.x;
    const int nt = bid & 31, ct = (bid >> 5) & 3, ks = (bid >> 7) & 3, b = bid >> 9;
    const int n0 = nt * 64, c0 = ct * 64, k00 = ks * 512;
    __shared__ float sRT[16][68];
    __shared__ float sV[16][68];
    const int tid = threadIdx.x;
    const int ny = tid & 15, cx = tid >> 4;
    float acc[4][4] = {};
    const float* Rb = R + (size_t)b * N2 * N2;
    const float* Vb = V + (size_t)b * N2 * CH;
    for (int k0 = k00; k0 < k00 + 512; k0 += 16) {
        for (int idx = tid; idx < 1024; idx += 256) {
            const int nl = idx >> 4, kk = idx & 15;
            sRT[kk][nl] = Rb[(size_t)(n0 + nl) * N2 + k0 + kk];
        }
        for (int idx = tid; idx < 1024; idx += 256) {
            const int kk = idx >> 6, cl = idx & 63;
            sV[kk][cl] = Vb[(size_t)(k0 + kk) * CH + c0 + cl];
        }
        __syncthreads();
        #pragma unroll
        for (int kk = 0; kk < 16; ++kk) {
            const float4 av = *(const float4*)&sRT[kk][4 * ny];
            const float4 bv = *(const float4*)&sV[kk][4 * cx];
            acc[0][0] += av.x * bv.x; acc[0][1] += av.x * bv.y; acc[0][2] += av.x * bv.z; acc[0][3] += av.x * bv.w;
            acc[1][0] += av.y * bv.x; acc[1][1] += av.y * bv.y; acc[1][2] += av.y * bv.z; acc[1][3] += av.y * bv.w;
            acc[2][0] += av.z * bv.x; acc[2][1] += av.z * bv.y; acc[2][2] += av.z * bv.z; acc[2][3] += av.z * bv.w;
            acc[3][0] += av.w * bv.x; acc[3][1] += av.w * bv.y; acc[3][2] += av.w * bv.z; acc[3][3] += av.w * bv.w;
        }
        __syncthreads();
    }
    #pragma unroll
    for (int i = 0; i < 4; ++i)
        #pragma unroll
        for (int j = 0; j < 4; ++j)
            atomicAdd(&att[((size_t)b * N2 + n0 + 4 * ny + i) * CH + c0 + 4 * cx + j], acc[i][j]);
}

// ---------------- out_projection + LN ----------------
__global__ void __launch_bounds__(256) outproj_k(
    const float* __restrict__ pf, const float* __restrict__ att,
    const float* __restrict__ WoutT,
    const float* __restrict__ bout, const float* __restrict__ g,
    const float* __restrict__ be, float* __restrict__ y) {
    const int b = blockIdx.x >> 8;
    const int n0 = (blockIdx.x & 255) * 8;
    const int tid = threadIdx.x;
    __shared__ float s_x[8][512];
    __shared__ float sred[8];
    for (int idx = tid; idx < 2048; idx += 256) {
        const int k = idx & 255, r = idx >> 8;
        s_x[r][k] = pf[((size_t)b * N2 + n0 + r) * CH + k];
        s_x[r][256 + k] = att[((size_t)b * N2 + n0 + r) * CH + k];
    }
    __syncthreads();
    float acc[8] = {0, 0, 0, 0, 0, 0, 0, 0};
    for (int k = 0; k < 512; ++k) {
        const float w = WoutT[(size_t)k * CH + tid];
        #pragma unroll
        for (int r = 0; r < 8; ++r) acc[r] += s_x[r][k] * w;
    }
    const float bo = bout[tid], gg = g[tid], bb = be[tid];
    #pragma unroll
    for (int r = 0; r < 8; ++r) {
        const float v = acc[r] + bo;
        float s1 = v, s2 = v * v;
        blockReduce2(s1, s2, sred);
        const float mu = s1 * (1.f / 256.f);
        const float var = s2 * (1.f / 256.f) - mu * mu;
        y[((size_t)b * N2 + n0 + r) * CH + tid] = (v - mu) * rsqrtf(var + 1e-5f) * gg + bb;
    }
}

// ---------------- fused FFN + residual + LN + pred head ----------------
__global__ void __launch_bounds__(256) ffn_k(
    const float* __restrict__ y, const float* __restrict__ Wf1T,
    const float* __restrict__ bf1, const float* __restrict__ Wf2T,
    const float* __restrict__ bf2, const float* __restrict__ gln,
    const float* __restrict__ bln, const float* __restrict__ Wpred,
    const float* __restrict__ bpred, const float* __restrict__ pos,
    float* __restrict__ y2, float* __restrict__ out1,
    float* __restrict__ out2) {
    const int b = blockIdx.x >> 8;
    const int n0 = (blockIdx.x & 255) * 8;
    const int tid = threadIdx.x;
    __shared__ float s_y[8][256];
    __shared__ float s_h[8][1024];
    __shared__ float sred[8];
    for (int idx = tid; idx < 2048; idx += 256) {
        const int c = idx & 255, r = idx >> 8;
        s_y[r][c] = y[((size_t)b * N2 + n0 + r) * CH + c];
    }
    __syncthreads();
    float acc[4][8] = {};
    for (int c = 0; c < 256; ++c) {
        float yv[8];
        #pragma unroll
        for (int r = 0; r < 8; ++r) yv[r] = s_y[r][c];
        #pragma unroll
        for (int fi = 0; fi < 4; ++fi) {
            const float w = Wf1T[(size_t)c * FFNC + fi * 256 + tid];
            #pragma unroll
            for (int r = 0; r < 8; ++r) acc[fi][r] += yv[r] * w;
        }
    }
    #pragma unroll
    for (int fi = 0; fi < 4; ++fi) {
        const int f = fi * 256 + tid;
        const float bb = bf1[f];
        #pragma unroll
        for (int r = 0; r < 8; ++r) s_h[r][f] = fmaxf(acc[fi][r] + bb, 0.f);
    }
    __syncthreads();
    float a2[8] = {0, 0, 0, 0, 0, 0, 0, 0};
    for (int f = 0; f < 1024; ++f) {
        const float w = Wf2T[(size_t)f * CH + tid];
        #pragma unroll
        for (int r = 0; r < 8; ++r) a2[r] += s_h[r][f] * w;
    }
    const float bfv = bf2[tid], gg = gln[tid], bb2 = bln[tid];
    const float wp0 = Wpred[tid], wp1 = Wpred[CH + tid];
    #pragma unroll
    for (int r = 0; r < 8; ++r) {
        const int n = n0 + r;
        const float v = a2[r] + bfv + s_y[r][tid];
        float s1 = v, s2 = v * v;
        blockReduce2(s1, s2, sred);
        const float mu = s1 * (1.f / 256.f);
        const float var = s2 * (1.f / 256.f) - mu * mu;
        const float xo = (v - mu) * rsqrtf(var + 1e-5f) * gg + bb2;
        y2[((size_t)b * N2 + n) * CH + tid] = xo;
        float d0 = wp0 * xo, d1 = wp1 * xo;
        blockReduce2(d0, d1, sred);
        if (tid == 0) {
            const float c0v = d0 + bpred[0] + pos[((size_t)b * N2 + n) * 2 + 0];
            const float c1v = d1 + bpred[1] + pos[((size_t)b * N2 + n) * 2 + 1];
            out2[((size_t)b * 2 + 0) * N2 + n] = c0v;
            out2[((size_t)b * 2 + 1) * N2 + n] = c1v;
            out1[((size_t)b * N2 + n) * 2 + 0] = c0v;
            out1[((size_t)b * N2 + n) * 2 + 1] = c1v;
        }
    }
}

// ---------------- transpose xo -> out0 [b][c][n] f32 ----------------
__global__ void __launch_bounds__(256) out_x_k(
    const float* __restrict__ y2, float* __restrict__ out0) {
    __shared__ float t[32][33];
    const int bid = blockIdx.x;                      // 2*64*8 = 1024
    const int ct = bid & 7, nt = (bid >> 3) & 63, b = bid >> 9;
    const int tx = threadIdx.x & 31, ty = threadIdx.x >> 5;
    #pragma unroll
    for (int i = 0; i < 4; ++i) {
        const int r = ty + i * 8;
        t[r][tx] = y2[((size_t)b * N2 + nt * 32 + r) * CH + ct * 32 + tx];
    }
    __syncthreads();
    #pragma unroll
    for (int i = 0; i < 4; ++i) {
        const int r = ty + i * 8;
        out0[((size_t)b * CH + ct * 32 + r) * N2 + nt * 32 + tx] = t[tx][r];
    }
}

// ---------------- launcher ----------------
extern "C" void kernel_launch(void* const* d_in, const int* in_sizes, int n_in,
                              void* d_out, int out_size, void* d_ws, size_t ws_size,
                              hipStream_t stream) {
    const float* ptsf  = (const float*)d_in[0];
    const float* ppos  = (const float*)d_in[1];
    const float* imgf  = (const float*)d_in[2];
    const float* ipos  = (const float*)d_in[3];
    const float* pcin  = (const float*)d_in[4];
    const float* icin  = (const float*)d_in[5];
    const float* Wp    = (const float*)d_in[6];
    const float* bp    = (const float*)d_in[7];
    const float* Wi    = (const float*)d_in[8];
    const float* bi    = (const float*)d_in[9];
    const float* Wqp   = (const float*)d_in[10];
    const float* bqp   = (const float*)d_in[11];
    const float* Wkp   = (const float*)d_in[12];
    const float* bkp   = (const float*)d_in[13];
    const float* Wout  = (const float*)d_in[14];
    const float* bout  = (const float*)d_in[15];
    const float* gout  = (const float*)d_in[16];
    const float* beo   = (const float*)d_in[17];
    const float* Wf1   = (const float*)d_in[18];
    const float* bf1   = (const float*)d_in[19];
    const float* Wf2   = (const float*)d_in[20];
    const float* bf2   = (const float*)d_in[21];
    const float* gln   = (const float*)d_in[22];
    const float* bln   = (const float*)d_in[23];
    const float* Wpred = (const float*)d_in[24];
    const float* bpred = (const float*)d_in[25];

    float* ws    = (float*)d_ws;
    float* Q     = ws + OFF_Q;
    float* imfT  = ws + OFF_IMFT;
    float* cpart = ws + OFF_CPART;
    float* att   = ws + OFF_CPART;          // alias: cpart dead after last red
    float* WiT   = ws + OFF_CPART;          // alias: dead once ipot writes cpart
    float* pcls  = ws + OFF_PCLS;
    float* icls  = ws + OFF_ICLS;
    float* bvec  = ws + OFF_BVEC;
    float* avec  = ws + OFF_AVEC;
    float* WoutT = ws + OFF_WOUTT;
    float* Wf1T  = ws + OFF_WF1T;
    float* Wf2T  = ws + OFF_WF2T;
    // post-att_gemm residents of the dead Q region:
    float* pf    = ws + OFF_Q;              // [2][2048][256]
    float* yb    = ws + OFF_Q + 1048576u;   // [2][2048][256]
    float* y2    = ws + OFF_Q + 2097152u;   // [2][2048][256]
    float* WpT   = ws + OFF_Q + 3145728u;   // [256][256]

    float* out0 = (float*)d_out;                     // x       [2,256,2048]
    float* out1 = out0 + (size_t)2 * CH * N2;        // new_pos [2,2048,2]
    float* out2 = out1 + (size_t)2 * N2 * 2;         // center  [2,2,2048]

    // prologue (img side + weight transposes in persistent regions)
    cls_max_k<<<16, 256, 0, stream>>>(pcin, icin, pcls, icls);
    transpose_k<<<64, 256, 0, stream>>>(Wi, WiT, 256, 256);
    proj_rows<<<512, 256, 0, stream>>>(imgf, WiT, bi, Wkp, bkp, ipos, imfT);
    transpose_k<<<128, 256, 0, stream>>>(Wout, WoutT, 256, 512);
    transpose_k<<<256, 256, 0, stream>>>(Wf1, Wf1T, 1024, 256);
    transpose_k<<<256, 256, 0, stream>>>(Wf2, Wf2T, 256, 1024);

    // IPOT: 100 iterations, kernel-boundary sync, 4 rows/block
    ipot_init_k<<<1024, 256, 0, stream>>>(Q, ppos, ipos, pcls, avec, cpart);
    for (int t = 1; t < 100; ++t) {
        ipot_red_k<<<64, 256, 0, stream>>>(cpart, icls, bvec);
        ipot_ur_k<<<1024, 256, 0, stream>>>(Q, ppos, ipos, pcls, bvec, avec, cpart);
    }
    ipot_red_k<<<64, 256, 0, stream>>>(cpart, icls, bvec);
    ipot_fin_k<<<1024, 256, 0, stream>>>(Q, pcls, bvec, avec);

    // attention GEMM (K-split x4, atomic accumulate)
    att_zero_k<<<1024, 256, 0, stream>>>(att);
    att_gemm<<<1024, 256, 0, stream>>>(Q, imfT, att);

    // pts projection (deferred; Q region now dead) + epilogue
    transpose_k<<<64, 256, 0, stream>>>(Wp, WpT, 256, 256);
    proj_rows<<<512, 256, 0, stream>>>(ptsf, WpT, bp, Wqp, bqp, ppos, pf);
    outproj_k<<<512, 256, 0, stream>>>(pf, att, WoutT, bout, gout, beo, yb);
    ffn_k<<<512, 256, 0, stream>>>(yb, Wf1T, bf1, Wf2T, bf2, gln, bln,
                                   Wpred, bpred, ppos, y2, out1, out2);
    out_x_k<<<1024, 256, 0, stream>>>(y2, out0);
}

// Round 9
// 2581.473 us; speedup vs baseline: 5.5993x; 1.0101x over previous
//
#include <hip/hip_runtime.h>
#include <hip/hip_bf16.h>

#define N2   2048
#define CH   256
#define FFNC 1024

typedef unsigned short ushort_t;
typedef unsigned int   uint_t;

// ---------------- workspace layout (float offsets), total 32.0MB ----------------
// Q stored as bf16: [2][2048][2048] ushorts = 4,194,304 float-slots at offset 0.
// post-att_gemm the Q region hosts pf/yb/y2/WpT.
#define OFF_QB     0u
#define OFF_IMFT   4194304u                  // [2][2048][256] f32
#define OFF_CPART  5242880u                  // [2][512][2048] f32; WiT pre-ipot, att after
#define OFF_PCLS   7340032u
#define OFF_ICLS   7344128u
#define OFF_BVEC   7348224u
#define OFF_AVEC   7352320u
#define OFF_WOUTT  7356416u                  // [512][256]
#define OFF_WF1T   7487488u                  // [256][1024]
#define OFF_WF2T   7749632u                  // [1024][256]  end = 8011776 floats

// ---------------- bf16 helpers ----------------
__device__ __forceinline__ float bf2f(uint_t u) {
    return __uint_as_float(u << 16);
}
__device__ __forceinline__ ushort_t f2bf(float f) {
    __hip_bfloat16 h = __float2bfloat16(f);   // RNE
    ushort_t u;
    __builtin_memcpy(&u, &h, 2);
    return u;
}

__device__ __forceinline__ void blockReduce2(float& x, float& y, float* sred) {
    #pragma unroll
    for (int off = 32; off; off >>= 1) {
        x += __shfl_xor(x, off);
        y += __shfl_xor(y, off);
    }
    const int wave = threadIdx.x >> 6, lane = threadIdx.x & 63;
    if (lane == 0) { sred[wave] = x; sred[4 + wave] = y; }
    __syncthreads();
    x = sred[0] + sred[1] + sred[2] + sred[3];
    y = sred[4] + sred[5] + sred[6] + sred[7];
    __syncthreads();
}

// ---------------- tiny prep kernels ----------------
__global__ void __launch_bounds__(256) cls_max_k(
    const float* __restrict__ pc, const float* __restrict__ ic,
    float* __restrict__ pcls, float* __restrict__ icls) {
    const int g = blockIdx.x * 256 + threadIdx.x;  // 4096
    const int b = g >> 11, n = g & 2047;
    float m1 = -1e30f, m2 = -1e30f;
    #pragma unroll
    for (int k = 0; k < 10; ++k) {
        const float v1 = pc[((size_t)b * 10 + k) * N2 + n];
        const float v2 = ic[((size_t)b * 10 + k) * N2 + n];
        m1 = fmaxf(m1, 1.f / (1.f + __expf(-v1)));
        m2 = fmaxf(m2, 1.f / (1.f + __expf(-v2)));
    }
    pcls[g] = m1; icls[g] = m2;
}

__global__ void __launch_bounds__(256) transpose_k(
    const float* __restrict__ in, float* __restrict__ out, int R, int C) {
    __shared__ float t[32][33];
    const int nct = C >> 5;
    const int bx = blockIdx.x % nct, by = blockIdx.x / nct;
    const int c0 = bx * 32, r0 = by * 32;
    const int tx = threadIdx.x & 31, ty = threadIdx.x >> 5;
    #pragma unroll
    for (int i = 0; i < 4; ++i) {
        const int r = ty + i * 8;
        t[r][tx] = in[(size_t)(r0 + r) * C + c0 + tx];
    }
    __syncthreads();
    #pragma unroll
    for (int i = 0; i < 4; ++i) {
        const int r = ty + i * 8;
        out[(size_t)(c0 + r) * R + r0 + tx] = t[tx][r];
    }
}

// proj + pos-embed
__global__ void __launch_bounds__(256) proj_rows(
    const float* __restrict__ F, const float* __restrict__ WT,
    const float* __restrict__ bias, const float* __restrict__ Wpos,
    const float* __restrict__ bpos, const float* __restrict__ pos,
    float* __restrict__ outb) {
    const int b = blockIdx.x >> 8;
    const int n0 = (blockIdx.x & 255) * 8;
    const int tid = threadIdx.x;
    __shared__ float s_x[8][256];
    for (int idx = tid; idx < 2048; idx += 256) {
        const int r = idx & 7, c = idx >> 3;
        s_x[r][c] = F[((size_t)b * CH + c) * N2 + n0 + r];
    }
    __syncthreads();
    float acc[8] = {0, 0, 0, 0, 0, 0, 0, 0};
    for (int c = 0; c < 256; ++c) {
        const float w = WT[(size_t)c * CH + tid];
        #pragma unroll
        for (int r = 0; r < 8; ++r) acc[r] += s_x[r][c] * w;
    }
    const float badd = bias[tid] + bpos[tid];
    const float w0 = Wpos[tid * 2 + 0], w1 = Wpos[tid * 2 + 1];
    #pragma unroll
    for (int r = 0; r < 8; ++r) {
        const int n = n0 + r;
        const float p0 = pos[((size_t)b * N2 + n) * 2 + 0];
        const float p1 = pos[((size_t)b * N2 + n) * 2 + 1];
        outb[((size_t)b * N2 + n) * CH + tid] = acc[r] + badd + w0 * p0 + w1 * p1;
    }
}

// ---------------- IPOT (bf16 Q, 4 rows/block, grid 1024) ----------------
// Thread t owns contiguous cols {8t..8t+7}: one uint4 (8 bf16) per row.

__device__ __forceinline__ void load_cols8(const float* ipos, int batch, int tid,
                                           float* ixr, float* iyr) {
    const float4* ip4 = (const float4*)(ipos + (size_t)batch * (N2 * 2));
    #pragma unroll
    for (int m = 0; m < 4; ++m) {
        const float4 v = ip4[4 * tid + m];
        ixr[2 * m + 0] = v.x; iyr[2 * m + 0] = v.y;
        ixr[2 * m + 1] = v.z; iyr[2 * m + 1] = v.w;
    }
}

__device__ __forceinline__ void unpack8(const uint4 v, float* q) {
    q[0] = bf2f(v.x & 0xffffu); q[1] = bf2f(v.x >> 16);
    q[2] = bf2f(v.y & 0xffffu); q[3] = bf2f(v.y >> 16);
    q[4] = bf2f(v.z & 0xffffu); q[5] = bf2f(v.z >> 16);
    q[6] = bf2f(v.w & 0xffffu); q[7] = bf2f(v.w >> 16);
}

__device__ __forceinline__ uint4 pack8(const float* q) {
    uint4 v;
    v.x = (uint_t)f2bf(q[0]) | ((uint_t)f2bf(q[1]) << 16);
    v.y = (uint_t)f2bf(q[2]) | ((uint_t)f2bf(q[3]) << 16);
    v.z = (uint_t)f2bf(q[4]) | ((uint_t)f2bf(q[5]) << 16);
    v.w = (uint_t)f2bf(q[6]) | ((uint_t)f2bf(q[7]) << 16);
    return v;
}

// init: Q1 = max(G,1e-6) (bf16-rounded); a1 = pcls/(rowsum/2048+1e-6); cs -> cpart
__global__ void __launch_bounds__(256, 4) ipot_init_k(
    ushort_t* __restrict__ Q, const float* __restrict__ ppos, const float* __restrict__ ipos,
    const float* __restrict__ pcls, float* __restrict__ avec, float* __restrict__ cpart) {
    const int blk = blockIdx.x;
    const int batch = blk >> 9;
    const int p = blk & 511;
    const int r0 = p * 4;
    const int tid = threadIdx.x, wave = tid >> 6, lane = tid & 63;
    __shared__ float s_tot[4][4];

    float ixr[8], iyr[8];
    load_cols8(ipos, batch, tid, ixr, iyr);
    float px[4], py[4], pcl4[4];
    #pragma unroll
    for (int j = 0; j < 4; ++j) {
        px[j] = ppos[((size_t)batch * N2 + r0 + j) * 2 + 0];
        py[j] = ppos[((size_t)batch * N2 + r0 + j) * 2 + 1];
        pcl4[j] = pcls[batch * N2 + r0 + j];
    }
    ushort_t* Qb = Q + (size_t)batch * N2 * N2;
    float cs[8] = {0, 0, 0, 0, 0, 0, 0, 0};

    float qn[4][8];
    float rd[4];
    #pragma unroll
    for (int jj = 0; jj < 4; ++jj) {
        rd[jj] = 0.f;
        #pragma unroll
        for (int k = 0; k < 8; ++k) {
            const float dx = px[jj] - ixr[k], dy = py[jj] - iyr[k];
            const float v = fmaxf(__expf(-0.1f * sqrtf(dx * dx + dy * dy)), 1e-6f);
            qn[jj][k] = bf2f(f2bf(v));       // self-consistent rounded value
            rd[jj] += qn[jj][k];
        }
        ((uint4*)(Qb + (size_t)(r0 + jj) * N2))[tid] = pack8(qn[jj]);
    }
    #pragma unroll
    for (int off = 32; off; off >>= 1) {
        #pragma unroll
        for (int jj = 0; jj < 4; ++jj) rd[jj] += __shfl_xor(rd[jj], off);
    }
    if (lane == 0) {
        #pragma unroll
        for (int jj = 0; jj < 4; ++jj) s_tot[wave][jj] = rd[jj];
    }
    __syncthreads();
    #pragma unroll
    for (int jj = 0; jj < 4; ++jj) {
        const float tot = s_tot[0][jj] + s_tot[1][jj] + s_tot[2][jj] + s_tot[3][jj];
        const float a = pcl4[jj] / (tot * (1.f / 2048.f) + 1e-6f);
        if (tid == 0) avec[batch * N2 + r0 + jj] = a;
        #pragma unroll
        for (int k = 0; k < 8; ++k) cs[k] += a * qn[jj][k];
    }
    float4* cp4 = (float4*)(cpart + ((size_t)batch * 512 + p) * N2);
    float4 l, h4;
    l.x = cs[0]; l.y = cs[1]; l.z = cs[2]; l.w = cs[3];
    h4.x = cs[4]; h4.y = cs[5]; h4.z = cs[6]; h4.w = cs[7];
    cp4[2 * tid] = l; cp4[2 * tid + 1] = h4;
}

// reduce: bvec = icls / (colsum of 512 cpart partials + 1e-6). grid 64.
__global__ void __launch_bounds__(256) ipot_red_k(
    const float* __restrict__ cpart, const float* __restrict__ icls,
    float* __restrict__ bvec) {
    const int b = blockIdx.x >> 5;
    const int c0 = (blockIdx.x & 31) * 64;
    const int tid = threadIdx.x;
    const int c = tid & 63, pg = tid >> 6;   // 4 partial groups
    __shared__ float s_part[4][64];
    const float* cpb = cpart + (size_t)b * 512 * N2 + c0 + c;
    float s = 0.f;
    #pragma unroll 8
    for (int k = 0; k < 128; ++k) s += cpb[(size_t)(pg + 4 * k) * N2];
    s_part[pg][c] = s;
    __syncthreads();
    if (tid < 64) {
        const float tot = s_part[0][tid] + s_part[1][tid] + s_part[2][tid] + s_part[3][tid];
        bvec[b * N2 + c0 + tid] = icls[b * N2 + c0 + tid] / (tot + 1e-6f);
    }
}

// one iteration: Q <- max(G*(a*Q*b),1e-6) (bf16); a <- pcls/(Q.b+1e-6); cs -> cpart
__global__ void __launch_bounds__(256, 4) ipot_ur_k(
    ushort_t* __restrict__ Q, const float* __restrict__ ppos, const float* __restrict__ ipos,
    const float* __restrict__ pcls, const float* __restrict__ bvec,
    float* __restrict__ avec, float* __restrict__ cpart) {
    const int blk = blockIdx.x;
    const int batch = blk >> 9;
    const int p = blk & 511;
    const int r0 = p * 4;
    const int tid = threadIdx.x, wave = tid >> 6, lane = tid & 63;
    __shared__ float s_tot[4][4];

    float ixr[8], iyr[8];
    load_cols8(ipos, batch, tid, ixr, iyr);
    float bb[8];
    {
        const float4* bv4 = (const float4*)(bvec + (size_t)batch * N2);
        const float4 l = bv4[2 * tid], h4 = bv4[2 * tid + 1];
        bb[0] = l.x; bb[1] = l.y; bb[2] = l.z; bb[3] = l.w;
        bb[4] = h4.x; bb[5] = h4.y; bb[6] = h4.z; bb[7] = h4.w;
    }
    float px[4], py[4], pcl4[4], a_cur[4];
    #pragma unroll
    for (int j = 0; j < 4; ++j) {
        px[j] = ppos[((size_t)batch * N2 + r0 + j) * 2 + 0];
        py[j] = ppos[((size_t)batch * N2 + r0 + j) * 2 + 1];
        pcl4[j] = pcls[batch * N2 + r0 + j];
        a_cur[j] = avec[batch * N2 + r0 + j];
    }
    ushort_t* Qb = Q + (size_t)batch * N2 * N2;
    float cs[8] = {0, 0, 0, 0, 0, 0, 0, 0};

    float qn[4][8];
    float rd[4];
    #pragma unroll
    for (int jj = 0; jj < 4; ++jj) {
        uint4* row4 = (uint4*)(Qb + (size_t)(r0 + jj) * N2);
        float qv[8];
        unpack8(row4[tid], qv);
        rd[jj] = 0.f;
        const float a = a_cur[jj];
        #pragma unroll
        for (int k = 0; k < 8; ++k) {
            const float dx = px[jj] - ixr[k], dy = py[jj] - iyr[k];
            const float G = __expf(-0.1f * sqrtf(dx * dx + dy * dy));
            const float v = fmaxf(G * ((a * qv[k]) * bb[k]), 1e-6f);
            qn[jj][k] = bf2f(f2bf(v));       // rounded value actually stored
            rd[jj] += qn[jj][k] * bb[k];
        }
        row4[tid] = pack8(qn[jj]);
    }
    #pragma unroll
    for (int off = 32; off; off >>= 1) {
        #pragma unroll
        for (int jj = 0; jj < 4; ++jj) rd[jj] += __shfl_xor(rd[jj], off);
    }
    if (lane == 0) {
        #pragma unroll
        for (int jj = 0; jj < 4; ++jj) s_tot[wave][jj] = rd[jj];
    }
    __syncthreads();
    #pragma unroll
    for (int jj = 0; jj < 4; ++jj) {
        const float tot = s_tot[0][jj] + s_tot[1][jj] + s_tot[2][jj] + s_tot[3][jj];
        const float a = pcl4[jj] / (tot + 1e-6f);
        if (tid == 0) avec[batch * N2 + r0 + jj] = a;
        #pragma unroll
        for (int k = 0; k < 8; ++k) cs[k] += a * qn[jj][k];
    }
    float4* cp4 = (float4*)(cpart + ((size_t)batch * 512 + p) * N2);
    float4 l, h4;
    l.x = cs[0]; l.y = cs[1]; l.z = cs[2]; l.w = cs[3];
    h4.x = cs[4]; h4.y = cs[5]; h4.z = cs[6]; h4.w = cs[7];
    cp4[2 * tid] = l; cp4[2 * tid + 1] = h4;
}

// final: res = a*Q*b, row-L1-normalize, write into Q (bf16)
__global__ void __launch_bounds__(256, 4) ipot_fin_k(
    ushort_t* __restrict__ Q, const float* __restrict__ pcls,
    const float* __restrict__ bvec, const float* __restrict__ avec) {
    const int blk = blockIdx.x;
    const int batch = blk >> 9;
    const int p = blk & 511;
    const int r0 = p * 4;
    const int tid = threadIdx.x, wave = tid >> 6, lane = tid & 63;
    __shared__ float s_tot[4][4];

    float bb[8];
    {
        const float4* bv4 = (const float4*)(bvec + (size_t)batch * N2);
        const float4 l = bv4[2 * tid], h4 = bv4[2 * tid + 1];
        bb[0] = l.x; bb[1] = l.y; bb[2] = l.z; bb[3] = l.w;
        bb[4] = h4.x; bb[5] = h4.y; bb[6] = h4.z; bb[7] = h4.w;
    }
    float a4[4];
    #pragma unroll
    for (int j = 0; j < 4; ++j) a4[j] = avec[batch * N2 + r0 + j];
    ushort_t* Qb = Q + (size_t)batch * N2 * N2;

    float vv[4][8];
    float rs[4];
    #pragma unroll
    for (int jj = 0; jj < 4; ++jj) {
        uint4* row4 = (uint4*)(Qb + (size_t)(r0 + jj) * N2);
        float qv[8];
        unpack8(row4[tid], qv);
        rs[jj] = 0.f;
        const float a = a4[jj];
        #pragma unroll
        for (int k = 0; k < 8; ++k) {
            const float v = (a * qv[k]) * bb[k];
            vv[jj][k] = v;
            rs[jj] += v;
        }
    }
    #pragma unroll
    for (int off = 32; off; off >>= 1) {
        #pragma unroll
        for (int jj = 0; jj < 4; ++jj) rs[jj] += __shfl_xor(rs[jj], off);
    }
    if (lane == 0) {
        #pragma unroll
        for (int jj = 0; jj < 4; ++jj) s_tot[wave][jj] = rs[jj];
    }
    __syncthreads();
    #pragma unroll
    for (int jj = 0; jj < 4; ++jj) {
        const float tot = s_tot[0][jj] + s_tot[1][jj] + s_tot[2][jj] + s_tot[3][jj];
        const float sc = 1.f / fmaxf(tot, 1e-12f);
        float o[8];
        #pragma unroll
        for (int k = 0; k < 8; ++k) o[k] = vv[jj][k] * sc;
        ((uint4*)(Qb + (size_t)(r0 + jj) * N2))[tid] = pack8(o);
    }
}

// ---------------- att GEMM: att[b][n][c] = sum_m res~[b][n][m] * imfT[b][m][c]
__global__ void __launch_bounds__(256) att_zero_k(float* __restrict__ att) {
    const int idx = blockIdx.x * 256 + threadIdx.x;   // 262144 float4 = 1048576 floats
    float4 z; z.x = 0.f; z.y = 0.f; z.z = 0.f; z.w = 0.f;
    ((float4*)att)[idx] = z;
}

// grid 1024 = 2(b) x 4(ks) x 4(ct) x 32(nt). 64x64 tile, K-chunk 512, atomicAdd out.
__global__ void __launch_bounds__(256, 4) att_gemm(
    const ushort_t* __restrict__ R, const float* __restrict__ V, float* __restrict__ att) {
    const int bid = blockIdx.x;
    const int nt = bid & 31, ct = (bid >> 5) & 3, ks = (bid >> 7) & 3, b = bid >> 9;
    const int n0 = nt * 64, c0 = ct * 64, k00 = ks * 512;
    __shared__ float sRT[16][68];
    __shared__ float sV[16][68];
    const int tid = threadIdx.x;
    const int ny = tid & 15, cx = tid >> 4;
    float acc[4][4] = {};
    const ushort_t* Rb = R + (size_t)b * N2 * N2;
    const float* Vb = V + (size_t)b * N2 * CH;
    const int snl = tid & 63, skk0 = (tid >> 6) * 4;
    for (int k0 = k00; k0 < k00 + 512; k0 += 16) {
        {
            const uint2 v = *(const uint2*)&Rb[(size_t)(n0 + snl) * N2 + k0 + skk0];
            sRT[skk0 + 0][snl] = bf2f(v.x & 0xffffu);
            sRT[skk0 + 1][snl] = bf2f(v.x >> 16);
            sRT[skk0 + 2][snl] = bf2f(v.y & 0xffffu);
            sRT[skk0 + 3][snl] = bf2f(v.y >> 16);
        }
        for (int idx = tid; idx < 1024; idx += 256) {
            const int kk = idx >> 6, cl = idx & 63;
            sV[kk][cl] = Vb[(size_t)(k0 + kk) * CH + c0 + cl];
        }
        __syncthreads();
        #pragma unroll
        for (int kk = 0; kk < 16; ++kk) {
            const float4 av = *(const float4*)&sRT[kk][4 * ny];
            const float4 bv = *(const float4*)&sV[kk][4 * cx];
            acc[0][0] += av.x * bv.x; acc[0][1] += av.x * bv.y; acc[0][2] += av.x * bv.z; acc[0][3] += av.x * bv.w;
            acc[1][0] += av.y * bv.x; acc[1][1] += av.y * bv.y; acc[1][2] += av.y * bv.z; acc[1][3] += av.y * bv.w;
            acc[2][0] += av.z * bv.x; acc[2][1] += av.z * bv.y; acc[2][2] += av.z * bv.z; acc[2][3] += av.z * bv.w;
            acc[3][0] += av.w * bv.x; acc[3][1] += av.w * bv.y; acc[3][2] += av.w * bv.z; acc[3][3] += av.w * bv.w;
        }
        __syncthreads();
    }
    #pragma unroll
    for (int i = 0; i < 4; ++i)
        #pragma unroll
        for (int j = 0; j < 4; ++j)
            atomicAdd(&att[((size_t)b * N2 + n0 + 4 * ny + i) * CH + c0 + 4 * cx + j], acc[i][j]);
}

// ---------------- out_projection + LN ----------------
__global__ void __launch_bounds__(256) outproj_k(
    const float* __restrict__ pf, const float* __restrict__ att,
    const float* __restrict__ WoutT,
    const float* __restrict__ bout, const float* __restrict__ g,
    const float* __restrict__ be, float* __restrict__ y) {
    const int b = blockIdx.x >> 8;
    const int n0 = (blockIdx.x & 255) * 8;
    const int tid = threadIdx.x;
    __shared__ float s_x[8][512];
    __shared__ float sred[8];
    for (int idx = tid; idx < 2048; idx += 256) {
        const int k = idx & 255, r = idx >> 8;
        s_x[r][k] = pf[((size_t)b * N2 + n0 + r) * CH + k];
        s_x[r][256 + k] = att[((size_t)b * N2 + n0 + r) * CH + k];
    }
    __syncthreads();
    float acc[8] = {0, 0, 0, 0, 0, 0, 0, 0};
    for (int k = 0; k < 512; ++k) {
        const float w = WoutT[(size_t)k * CH + tid];
        #pragma unroll
        for (int r = 0; r < 8; ++r) acc[r] += s_x[r][k] * w;
    }
    const float bo = bout[tid], gg = g[tid], bb = be[tid];
    #pragma unroll
    for (int r = 0; r < 8; ++r) {
        const float v = acc[r] + bo;
        float s1 = v, s2 = v * v;
        blockReduce2(s1, s2, sred);
        const float mu = s1 * (1.f / 256.f);
        const float var = s2 * (1.f / 256.f) - mu * mu;
        y[((size_t)b * N2 + n0 + r) * CH + tid] = (v - mu) * rsqrtf(var + 1e-5f) * gg + bb;
    }
}

// ---------------- fused FFN + residual + LN + pred head ----------------
__global__ void __launch_bounds__(256) ffn_k(
    const float* __restrict__ y, const float* __restrict__ Wf1T,
    const float* __restrict__ bf1, const float* __restrict__ Wf2T,
    const float* __restrict__ bf2, const float* __restrict__ gln,
    const float* __restrict__ bln, const float* __restrict__ Wpred,
    const float* __restrict__ bpred, const float* __restrict__ pos,
    float* __restrict__ y2, float* __restrict__ out1,
    float* __restrict__ out2) {
    const int b = blockIdx.x >> 8;
    const int n0 = (blockIdx.x & 255) * 8;
    const int tid = threadIdx.x;
    __shared__ float s_y[8][256];
    __shared__ float s_h[8][1024];
    __shared__ float sred[8];
    for (int idx = tid; idx < 2048; idx += 256) {
        const int c = idx & 255, r = idx >> 8;
        s_y[r][c] = y[((size_t)b * N2 + n0 + r) * CH + c];
    }
    __syncthreads();
    float acc[4][8] = {};
    for (int c = 0; c < 256; ++c) {
        float yv[8];
        #pragma unroll
        for (int r = 0; r < 8; ++r) yv[r] = s_y[r][c];
        #pragma unroll
        for (int fi = 0; fi < 4; ++fi) {
            const float w = Wf1T[(size_t)c * FFNC + fi * 256 + tid];
            #pragma unroll
            for (int r = 0; r < 8; ++r) acc[fi][r] += yv[r] * w;
        }
    }
    #pragma unroll
    for (int fi = 0; fi < 4; ++fi) {
        const int f = fi * 256 + tid;
        const float bb = bf1[f];
        #pragma unroll
        for (int r = 0; r < 8; ++r) s_h[r][f] = fmaxf(acc[fi][r] + bb, 0.f);
    }
    __syncthreads();
    float a2[8] = {0, 0, 0, 0, 0, 0, 0, 0};
    for (int f = 0; f < 1024; ++f) {
        const float w = Wf2T[(size_t)f * CH + tid];
        #pragma unroll
        for (int r = 0; r < 8; ++r) a2[r] += s_h[r][f] * w;
    }
    const float bfv = bf2[tid], gg = gln[tid], bb2 = bln[tid];
    const float wp0 = Wpred[tid], wp1 = Wpred[CH + tid];
    #pragma unroll
    for (int r = 0; r < 8; ++r) {
        const int n = n0 + r;
        const float v = a2[r] + bfv + s_y[r][tid];
        float s1 = v, s2 = v * v;
        blockReduce2(s1, s2, sred);
        const float mu = s1 * (1.f / 256.f);
        const float var = s2 * (1.f / 256.f) - mu * mu;
        const float xo = (v - mu) * rsqrtf(var + 1e-5f) * gg + bb2;
        y2[((size_t)b * N2 + n) * CH + tid] = xo;
        float d0 = wp0 * xo, d1 = wp1 * xo;
        blockReduce2(d0, d1, sred);
        if (tid == 0) {
            const float c0v = d0 + bpred[0] + pos[((size_t)b * N2 + n) * 2 + 0];
            const float c1v = d1 + bpred[1] + pos[((size_t)b * N2 + n) * 2 + 1];
            out2[((size_t)b * 2 + 0) * N2 + n] = c0v;
            out2[((size_t)b * 2 + 1) * N2 + n] = c1v;
            out1[((size_t)b * N2 + n) * 2 + 0] = c0v;
            out1[((size_t)b * N2 + n) * 2 + 1] = c1v;
        }
    }
}

// ---------------- transpose xo -> out0 [b][c][n] f32 ----------------
__global__ void __launch_bounds__(256) out_x_k(
    const float* __restrict__ y2, float* __restrict__ out0) {
    __shared__ float t[32][33];
    const int bid = blockIdx.x;                      // 2*64*8 = 1024
    const int ct = bid & 7, nt = (bid >> 3) & 63, b = bid >> 9;
    const int tx = threadIdx.x & 31, ty = threadIdx.x >> 5;
    #pragma unroll
    for (int i = 0; i < 4; ++i) {
        const int r = ty + i * 8;
        t[r][tx] = y2[((size_t)b * N2 + nt * 32 + r) * CH + ct * 32 + tx];
    }
    __syncthreads();
    #pragma unroll
    for (int i = 0; i < 4; ++i) {
        const int r = ty + i * 8;
        out0[((size_t)b * CH + ct * 32 + r) * N2 + nt * 32 + tx] = t[tx][r];
    }
}

// ---------------- launcher ----------------
extern "C" void kernel_launch(void* const* d_in, const int* in_sizes, int n_in,
                              void* d_out, int out_size, void* d_ws, size_t ws_size,
                              hipStream_t stream) {
    const float* ptsf  = (const float*)d_in[0];
    const float* ppos  = (const float*)d_in[1];
    const float* imgf  = (const float*)d_in[2];
    const float* ipos  = (const float*)d_in[3];
    const float* pcin  = (const float*)d_in[4];
    const float* icin  = (const float*)d_in[5];
    const float* Wp    = (const float*)d_in[6];
    const float* bp    = (const float*)d_in[7];
    const float* Wi    = (const float*)d_in[8];
    const float* bi    = (const float*)d_in[9];
    const float* Wqp   = (const float*)d_in[10];
    const float* bqp   = (const float*)d_in[11];
    const float* Wkp   = (const float*)d_in[12];
    const float* bkp   = (const float*)d_in[13];
    const float* Wout  = (const float*)d_in[14];
    const float* bout  = (const float*)d_in[15];
    const float* gout  = (const float*)d_in[16];
    const float* beo   = (const float*)d_in[17];
    const float* Wf1   = (const float*)d_in[18];
    const float* bf1   = (const float*)d_in[19];
    const float* Wf2   = (const float*)d_in[20];
    const float* bf2   = (const float*)d_in[21];
    const float* gln   = (const float*)d_in[22];
    const float* bln   = (const float*)d_in[23];
    const float* Wpred = (const float*)d_in[24];
    const float* bpred = (const float*)d_in[25];

    float* ws    = (float*)d_ws;
    ushort_t* Qw = (ushort_t*)d_ws;          // bf16 Q at offset 0
    float* imfT  = ws + OFF_IMFT;
    float* cpart = ws + OFF_CPART;
    float* att   = ws + OFF_CPART;           // alias: cpart dead after last red
    float* WiT   = ws + OFF_CPART;           // alias: dead once ipot writes cpart
    float* pcls  = ws + OFF_PCLS;
    float* icls  = ws + OFF_ICLS;
    float* bvec  = ws + OFF_BVEC;
    float* avec  = ws + OFF_AVEC;
    float* WoutT = ws + OFF_WOUTT;
    float* Wf1T  = ws + OFF_WF1T;
    float* Wf2T  = ws + OFF_WF2T;
    // post-att_gemm residents of the dead Q region:
    float* pf    = ws + 0u;                  // [2][2048][256]
    float* yb    = ws + 1048576u;            // [2][2048][256]
    float* y2    = ws + 2097152u;            // [2][2048][256]
    float* WpT   = ws + 3145728u;            // [256][256]

    float* out0 = (float*)d_out;                     // x       [2,256,2048]
    float* out1 = out0 + (size_t)2 * CH * N2;        // new_pos [2,2048,2]
    float* out2 = out1 + (size_t)2 * N2 * 2;         // center  [2,2,2048]

    // prologue (img side + weight transposes in persistent regions)
    cls_max_k<<<16, 256, 0, stream>>>(pcin, icin, pcls, icls);
    transpose_k<<<64, 256, 0, stream>>>(Wi, WiT, 256, 256);
    proj_rows<<<512, 256, 0, stream>>>(imgf, WiT, bi, Wkp, bkp, ipos, imfT);
    transpose_k<<<128, 256, 0, stream>>>(Wout, WoutT, 256, 512);
    transpose_k<<<256, 256, 0, stream>>>(Wf1, Wf1T, 1024, 256);
    transpose_k<<<256, 256, 0, stream>>>(Wf2, Wf2T, 256, 1024);

    // IPOT: 100 iterations, kernel-boundary sync, bf16 Q
    ipot_init_k<<<1024, 256, 0, stream>>>(Qw, ppos, ipos, pcls, avec, cpart);
    for (int t = 1; t < 100; ++t) {
        ipot_red_k<<<64, 256, 0, stream>>>(cpart, icls, bvec);
        ipot_ur_k<<<1024, 256, 0, stream>>>(Qw, ppos, ipos, pcls, bvec, avec, cpart);
    }
    ipot_red_k<<<64, 256, 0, stream>>>(cpart, icls, bvec);
    ipot_fin_k<<<1024, 256, 0, stream>>>(Qw, pcls, bvec, avec);

    // attention GEMM (K-split x4, atomic accumulate, bf16 R)
    att_zero_k<<<1024, 256, 0, stream>>>(att);
    att_gemm<<<1024, 256, 0, stream>>>(Qw, imfT, att);

    // pts projection (deferred; Q region now dead) + epilogue
    transpose_k<<<64, 256, 0, stream>>>(Wp, WpT, 256, 256);
    proj_rows<<<512, 256, 0, stream>>>(ptsf, WpT, bp, Wqp, bqp, ppos, pf);
    outproj_k<<<512, 256, 0, stream>>>(pf, att, WoutT, bout, gout, beo, yb);
    ffn_k<<<512, 256, 0, stream>>>(yb, Wf1T, bf1, Wf2T, bf2, gln, bln,
                                   Wpred, bpred, ppos, y2, out1, out2);
    out_x_k<<<1024, 256, 0, stream>>>(y2, out0);
}